// Round 6
// baseline (1519.867 us; speedup 1.0000x reference)
//
#include <hip/hip_runtime.h>
#include <cstdint>
#include <cstddef>

typedef unsigned short u16;
typedef unsigned long long u64;
typedef __attribute__((ext_vector_type(8))) short short8;   // 8 x bf16 fragment
typedef __attribute__((ext_vector_type(4))) float f32x4;    // MFMA accumulator

constexpr int K_DIM = 2048;    // N_POS * D_MODEL (contraction dim for encode)
constexpr int S_DIM = 32768;   // D_SAE
constexpr int TOPK  = 32;
constexpr int CAP   = 256;     // max candidates per row (4 x 64 lanes in select)
#define EPS      0.06f         // bf16-GEMM max error bound (13 sigma, r3/r4-proven)
#define THR_EMIT 3.7f          // epilogue emit floor (capture needs v32a >= 3.82)
#define HIST_LO  3.5f          // histogram floor, 64 buckets of 0.04

// ---------------------------------------------------------------------------
__device__ __forceinline__ u16 f2bf(float f) {
    unsigned u = __float_as_uint(f);
    return (u16)((u + 0x7FFFu + ((u >> 16) & 1u)) >> 16);
}
__device__ __forceinline__ unsigned key_map(float f) {
    unsigned u = __float_as_uint(f);
    return (u & 0x80000000u) ? ~u : (u | 0x80000000u);
}
__device__ __forceinline__ float key_unmap(unsigned k) {
    unsigned u = (k & 0x80000000u) ? (k ^ 0x80000000u) : ~k;
    return __uint_as_float(u);
}

__global__ __launch_bounds__(256) void init_kernel(
    int* __restrict__ ccnt, int* __restrict__ flag,
    unsigned* __restrict__ hist, int M)
{
    const int tot = M * 66;                   // M + M + 64*M words
    for (int i = blockIdx.x * 256 + threadIdx.x; i < tot; i += gridDim.x * 256) {
        if (i < M) ccnt[i] = 0;
        else if (i < 2 * M) flag[i - M] = 0;
        else hist[i - 2 * M] = 0u;
    }
}

// x fp32 -> bf16 (for MFMA screening)
__global__ __launch_bounds__(256) void conv_x_kernel(
    const float* __restrict__ x, u16* __restrict__ hi, int n4)
{
    int i = blockIdx.x * 256 + threadIdx.x;
    if (i >= n4) return;
    float4 v = ((const float4*)x)[i];
    ushort4 h;
    h.x = f2bf(v.x); h.y = f2bf(v.y); h.z = f2bf(v.z); h.w = f2bf(v.w);
    ((ushort4*)hi)[i] = h;
}

// W_enc [K][S] f32 -> WT [S][K] f32 (exact, for rescoring) + Wh [S][K] bf16.
__global__ __launch_bounds__(256) void conv_wt_kernel(
    const float* __restrict__ W, float* __restrict__ WT, u16* __restrict__ Wh)
{
    __shared__ float tile[64][65];
    const int t  = threadIdx.x;
    const int s0 = blockIdx.x * 64;
    const int k0 = blockIdx.y * 64;
#pragma unroll
    for (int i = 0; i < 4; ++i) {
        int kl = (t >> 4) + i * 16;
        int sc = (t & 15) * 4;
        float4 v = *(const float4*)&W[(size_t)(k0 + kl) * S_DIM + s0 + sc];
        tile[kl][sc] = v.x; tile[kl][sc + 1] = v.y;
        tile[kl][sc + 2] = v.z; tile[kl][sc + 3] = v.w;
    }
    __syncthreads();
    const int klc = (t & 7) * 8;
#pragma unroll
    for (int i = 0; i < 2; ++i) {
        int sl = (t >> 3) + i * 32;
        float f[8];
        short8 h8;
#pragma unroll
        for (int j = 0; j < 8; ++j) {
            f[j] = tile[klc + j][sl];
            h8[j] = (short)f2bf(f[j]);
        }
        size_t o = (size_t)(s0 + sl) * K_DIM + k0 + klc;
        *(float4*)&WT[o]     = make_float4(f[0], f[1], f[2], f[3]);
        *(float4*)&WT[o + 4] = make_float4(f[4], f[5], f[6], f[7]);
        *(short8*)&Wh[o] = h8;
    }
}

// ---------------------------------------------------------------------------
// Screening GEMM, 256x256 8-phase schedule (verified r5). K-loop UNCHANGED.
// Epilogue now additionally: emits candidates (v >= THR_EMIT) as packed
// (key(v)<<32 | col) with per-row atomic append, and builds a 64-bucket
// global histogram of values >= HIST_LO (width 0.04) for per-row thresholds.
// ---------------------------------------------------------------------------
__device__ __forceinline__ void gl16(const u16* g, u16* s) {
    __builtin_amdgcn_global_load_lds(
        (const __attribute__((address_space(1))) unsigned int*)g,
        (__attribute__((address_space(3))) unsigned int*)s,
        16, 0, 0);
}

#define LGKM0  do { asm volatile("s_waitcnt lgkmcnt(0)" ::: "memory"); \
                    __builtin_amdgcn_sched_barrier(0); } while (0)
#define VMW(n) asm volatile("s_waitcnt vmcnt(" #n ")" ::: "memory")
#define BAR    do { __builtin_amdgcn_s_barrier(); \
                    __builtin_amdgcn_sched_barrier(0); } while (0)

__global__ __launch_bounds__(512, 2) void gemm_mfma_kernel(
    const u16* __restrict__ A, const u16* __restrict__ B,
    const float* __restrict__ bias, float* __restrict__ C,
    u64* __restrict__ emit, int* __restrict__ ccnt,
    unsigned* __restrict__ hist, int row0)
{
    __shared__ alignas(16) u16 sA[2][256 * 64];
    __shared__ alignas(16) u16 sB[2][256 * 64];

    const int t = threadIdx.x;
    const int lane = t & 63;
    const int w = t >> 6;
    const int wm = w >> 2, wn = w & 3;

    const int nwg = gridDim.x;
    const int q = nwg >> 3;
    const int bid = blockIdx.x;
    const int wg = (bid & 7) * q + (bid >> 3);
    const int bm = wg >> 7;
    const int bn = wg & 127;

    const u16* Ab = A + (size_t)bm * 256 * K_DIM;
    const u16* Bb = B + (size_t)bn * 256 * K_DIM;

    const int w2  = w * 2;
    const int lr3 = lane >> 3;
    const int csw = ((lane & 7) ^ lr3) * 8;

    const int rl = lane & 15, kq = lane >> 4;
    const int swz = rl & 7;
    const int ac0 = (kq ^ swz) * 8;
    const int ac1 = ((4 + kq) ^ swz) * 8;
    const int arow = (wm * 16 + rl) * 64;
    const int brow = (wn * 16 + rl) * 64;

    f32x4 acc[8][4];
#pragma unroll
    for (int m = 0; m < 8; ++m)
#pragma unroll
        for (int n = 0; n < 4; ++n) acc[m][n] = (f32x4){0.f, 0.f, 0.f, 0.f};

    auto stA = [&](int half, int j, int kt, int buf) {
        const u16* src = Ab + (size_t)(half * 128 + (w2 + j) * 8 + lr3) * K_DIM
                            + kt * 64 + csw;
        gl16(src, &sA[buf][half * 8192 + (w2 + j) * 512]);
    };
    auto stB = [&](int half, int j, int kt, int buf) {
        const u16* src = Bb + (size_t)(half * 128 + (w2 + j) * 8 + lr3) * K_DIM
                            + kt * 64 + csw;
        gl16(src, &sB[buf][half * 8192 + (w2 + j) * 512]);
    };

    stA(0, 0, 0, 0); stA(0, 1, 0, 0);
    stB(0, 0, 0, 0); stB(0, 1, 0, 0);
    stB(1, 0, 0, 0); stB(1, 1, 0, 0);
    stA(1, 0, 0, 0); stA(1, 1, 0, 0);
    VMW(4);
    BAR;

    short8 af[4][2], bf[4][2];

#pragma unroll 1
    for (int kt = 0; kt < 32; ++kt) {
        const int cur = kt & 1, nxt = cur ^ 1;
        const bool more = (kt < 31);

        // ---- P1
#pragma unroll
        for (int m = 0; m < 4; ++m) {
            af[m][0] = *(const short8*)&sA[cur][arow + m * 2048 + ac0];
            af[m][1] = *(const short8*)&sA[cur][arow + m * 2048 + ac1];
        }
#pragma unroll
        for (int n = 0; n < 2; ++n) {
            bf[n][0] = *(const short8*)&sB[cur][brow + n * 4096 + ac0];
            bf[n][1] = *(const short8*)&sB[cur][brow + n * 4096 + ac1];
        }
        if (more) { stA(0, 0, kt + 1, nxt); stA(0, 1, kt + 1, nxt); }
        __builtin_amdgcn_s_barrier();
        LGKM0;
        __builtin_amdgcn_s_setprio(1);
#pragma unroll
        for (int m = 0; m < 4; ++m)
#pragma unroll
            for (int n = 0; n < 2; ++n)
#pragma unroll
                for (int kk = 0; kk < 2; ++kk)
                    acc[m][n] = __builtin_amdgcn_mfma_f32_16x16x32_bf16(
                        af[m][kk], bf[n][kk], acc[m][n], 0, 0, 0);
        __builtin_amdgcn_s_setprio(0);
        if (more) VMW(4); else VMW(2);
        BAR;

        // ---- P2
#pragma unroll
        for (int n = 2; n < 4; ++n) {
            bf[n][0] = *(const short8*)&sB[cur][brow + n * 4096 + ac0];
            bf[n][1] = *(const short8*)&sB[cur][brow + n * 4096 + ac1];
        }
        if (more) { stB(0, 0, kt + 1, nxt); stB(0, 1, kt + 1, nxt); }
        __builtin_amdgcn_s_barrier();
        LGKM0;
        __builtin_amdgcn_s_setprio(1);
#pragma unroll
        for (int m = 0; m < 4; ++m)
#pragma unroll
            for (int n = 2; n < 4; ++n)
#pragma unroll
                for (int kk = 0; kk < 2; ++kk)
                    acc[m][n] = __builtin_amdgcn_mfma_f32_16x16x32_bf16(
                        af[m][kk], bf[n][kk], acc[m][n], 0, 0, 0);
        __builtin_amdgcn_s_setprio(0);
        if (more) VMW(4); else VMW(0);
        BAR;

        // ---- P3
#pragma unroll
        for (int m = 0; m < 4; ++m) {
            af[m][0] = *(const short8*)&sA[cur][arow + (m + 4) * 2048 + ac0];
            af[m][1] = *(const short8*)&sA[cur][arow + (m + 4) * 2048 + ac1];
        }
        if (more) { stB(1, 0, kt + 1, nxt); stB(1, 1, kt + 1, nxt); }
        __builtin_amdgcn_s_barrier();
        LGKM0;
        __builtin_amdgcn_s_setprio(1);
#pragma unroll
        for (int m = 0; m < 4; ++m)
#pragma unroll
            for (int n = 2; n < 4; ++n)
#pragma unroll
                for (int kk = 0; kk < 2; ++kk)
                    acc[m + 4][n] = __builtin_amdgcn_mfma_f32_16x16x32_bf16(
                        af[m][kk], bf[n][kk], acc[m + 4][n], 0, 0, 0);
        __builtin_amdgcn_s_setprio(0);
        BAR;

        // ---- P4
        if (more) { stA(1, 0, kt + 1, nxt); stA(1, 1, kt + 1, nxt); }
        __builtin_amdgcn_s_barrier();
        __builtin_amdgcn_s_setprio(1);
#pragma unroll
        for (int m = 0; m < 4; ++m)
#pragma unroll
            for (int n = 0; n < 2; ++n)
#pragma unroll
                for (int kk = 0; kk < 2; ++kk)
                    acc[m + 4][n] = __builtin_amdgcn_mfma_f32_16x16x32_bf16(
                        af[m][kk], bf[n][kk], acc[m + 4][n], 0, 0, 0);
        __builtin_amdgcn_s_setprio(0);
        if (more) VMW(4);
        BAR;
    }

    // epilogue: C/D layout col = lane&15, row = (lane>>4)*4 + reg
    const int colB = bn * 256 + wn * 16 + rl;
    const int rowBl = bm * 256 + wm * 16 + kq * 4;    // local row base
    float bv[4];
#pragma unroll
    for (int n = 0; n < 4; ++n) bv[n] = bias[colB + n * 64];
#pragma unroll
    for (int m = 0; m < 8; ++m)
#pragma unroll
        for (int n = 0; n < 4; ++n)
#pragma unroll
            for (int rr = 0; rr < 4; ++rr) {
                const int lrow = rowBl + m * 32 + rr;
                const float v = acc[m][n][rr] + bv[n];
                C[(size_t)lrow * S_DIM + colB + n * 64] = v;
                if (v >= HIST_LO) {
                    const int grow = row0 + lrow;
                    int b = (int)((v - HIST_LO) * 25.0f);
                    if (b > 63) b = 63;
                    atomicAdd(&hist[(size_t)grow * 64 + b], 1u);
                    if (v >= THR_EMIT) {
                        int p = atomicAdd(&ccnt[grow], 1);
                        if (p < CAP)
                            emit[(size_t)grow * CAP + p] =
                                ((u64)key_map(v) << 32) | (unsigned)(colB + n * 64);
                    }
                }
            }
}

// ---------------------------------------------------------------------------
// thr: per-row suffix scan of the 64-bucket histogram -> refined threshold
//   T_eff = max(THR_EMIT, bucket_lo(32nd) - 2*EPS). Flags rows needing the
//   fallback (v32a < HIST_LO or emit overflow).
// ---------------------------------------------------------------------------
__global__ __launch_bounds__(64) void thr_kernel(
    const unsigned* __restrict__ hist, const int* __restrict__ ccnt,
    float* __restrict__ thrv, int* __restrict__ flag, int row0)
{
    const int row = row0 + blockIdx.x * 64 + threadIdx.x;
    const unsigned* h = hist + (size_t)row * 64;
    unsigned acc = 0;
    int b = -1;
    for (int j = 63; j >= 0; --j) {
        acc += h[j];
        if (acc >= (unsigned)TOPK) { b = j; break; }
    }
    float teff = THR_EMIT;
    if (b < 0 || ccnt[row] > CAP) {
        flag[row] = 1;
    } else {
        float thr = HIST_LO + 0.04f * b - 2.0f * EPS - 1e-4f;
        teff = fmaxf(THR_EMIT, thr);
    }
    thrv[row] = teff;
}

// ---------------------------------------------------------------------------
// Rescore: exact fp32 dot for candidates passing the refined threshold.
// ---------------------------------------------------------------------------
__global__ __launch_bounds__(256) void rescore_kernel(
    const float* __restrict__ x, const float* __restrict__ WT,
    const float* __restrict__ benc, const u64* __restrict__ emit,
    const int* __restrict__ ccnt, const float* __restrict__ thrv,
    float* __restrict__ resc, int row0)
{
    const int row = row0 + blockIdx.x;
    const int t = threadIdx.x;
    const int w = t >> 6, l = t & 63;
    int cnt = ccnt[row]; if (cnt > CAP) cnt = CAP;
    const float thr = thrv[row];

    __shared__ float xs[K_DIM];
    const float* xr = x + (size_t)row * K_DIM;
    for (int i = t * 4; i < K_DIM; i += 1024)
        *(float4*)&xs[i] = *(const float4*)&xr[i];
    __syncthreads();

    for (int c = w; c < cnt; c += 4) {
        const u64 pk = emit[(size_t)row * CAP + c];
        const float approx = key_unmap((unsigned)(pk >> 32));
        if (approx < thr) {
            if (l == 0) resc[(size_t)row * CAP + c] = -3e38f;
            continue;
        }
        const int s = (int)(pk & 0xFFFFFFFFu);
        const float* wc = WT + (size_t)s * K_DIM;
        float acc = 0.f;
#pragma unroll
        for (int j = 0; j < 32; ++j)
            acc = fmaf(xs[l + 64 * j], wc[l + 64 * j], acc);
#pragma unroll
        for (int d = 1; d < 64; d <<= 1) acc += __shfl_xor(acc, d);
        if (l == 0) resc[(size_t)row * CAP + c] = acc + benc[s];
    }
}

// ---------------------------------------------------------------------------
// Select: exact top-32 (value desc, index asc) + exactness validation:
//   v32_rescored >= T_eff + EPS  proves no non-candidate can be top-32.
// ---------------------------------------------------------------------------
__global__ __launch_bounds__(64) void select_kernel(
    const float* __restrict__ resc, const u64* __restrict__ emit,
    const int* __restrict__ ccnt, const float* __restrict__ thrv,
    float* __restrict__ tv, int* __restrict__ ti, int* __restrict__ flag,
    int row0)
{
    const int row = row0 + blockIdx.x;
    const int l = threadIdx.x;
    int cnt = ccnt[row]; if (cnt > CAP) cnt = CAP;

    float v[4] = {0.f, 0.f, 0.f, 0.f};
    int   s[4] = {-1, -1, -1, -1};
    u64   p[4] = {0, 0, 0, 0};
#pragma unroll
    for (int j = 0; j < 4; ++j) {
        int c = l + j * 64;
        if (c < cnt) {
            s[j] = (int)(emit[(size_t)row * CAP + c] & 0xFFFFFFFFu);
            v[j] = resc[(size_t)row * CAP + c];
            p[j] = ((u64)key_map(v[j]) << 32) | (unsigned)(~s[j]);
        }
    }

    float* tvr = tv + (size_t)row * TOPK;
    int*   tir = ti + (size_t)row * TOPK;
    float v32f = -3e38f;
#pragma unroll 1
    for (int r = 0; r < TOPK; ++r) {
        u64 m = p[0];
        if (p[1] > m) m = p[1];
        if (p[2] > m) m = p[2];
        if (p[3] > m) m = p[3];
#pragma unroll
        for (int d = 1; d < 64; d <<= 1) {
            u64 o = __shfl_xor(m, d);
            if (o > m) m = o;
        }
        if (r == TOPK - 1) v32f = key_unmap((unsigned)(m >> 32));
        if (p[0] == m)      { tvr[r] = v[0]; tir[r] = s[0] < 0 ? 0 : s[0]; p[0] = 0; }
        else if (p[1] == m) { tvr[r] = v[1]; tir[r] = s[1] < 0 ? 0 : s[1]; p[1] = 0; }
        else if (p[2] == m) { tvr[r] = v[2]; tir[r] = s[2] < 0 ? 0 : s[2]; p[2] = 0; }
        else if (p[3] == m) { tvr[r] = v[3]; tir[r] = s[3] < 0 ? 0 : s[3]; p[3] = 0; }
    }
    if (l == 0) {
        if (ccnt[row] > CAP || v32f < thrv[row] + EPS) flag[row] = 1;
    }
}

// ---------------------------------------------------------------------------
// Fallback (flag-guarded, normally 0 active rows): r4's verified exact
// histogram screen over the pre row, then rescore + select.
// ---------------------------------------------------------------------------
__global__ __launch_bounds__(256) void fb_screen_kernel(
    const float* __restrict__ pre, u64* __restrict__ emit,
    int* __restrict__ ccnt, const int* __restrict__ flag, int row0)
{
    const int grow = row0 + blockIdx.x;
    if (!flag[grow]) return;

    __shared__ unsigned hist[2048];
    __shared__ unsigned partial[256];
    __shared__ unsigned sh_tk;
    __shared__ int cnt;

    const int t = threadIdx.x;
    const float* prow = pre + (size_t)blockIdx.x * S_DIM;

    for (int i = t; i < 2048; i += 256) hist[i] = 0;
    if (t == 0) cnt = 0;
    __syncthreads();

    for (int i = t * 4; i < S_DIM; i += 1024) {
        float4 v = *(const float4*)(prow + i);
        unsigned k0 = key_map(v.x), k1 = key_map(v.y),
                 k2 = key_map(v.z), k3 = key_map(v.w);
        if (k0 >= 0xC0000000u) atomicAdd(&hist[(k0 >> 19) - 6144], 1u);
        if (k1 >= 0xC0000000u) atomicAdd(&hist[(k1 >> 19) - 6144], 1u);
        if (k2 >= 0xC0000000u) atomicAdd(&hist[(k2 >> 19) - 6144], 1u);
        if (k3 >= 0xC0000000u) atomicAdd(&hist[(k3 >> 19) - 6144], 1u);
    }
    __syncthreads();

    unsigned ps = 0;
#pragma unroll
    for (int j = 0; j < 8; ++j) ps += hist[t * 8 + j];
    partial[t] = ps;
    __syncthreads();

    if (t == 0) {
        unsigned acc = 0;
        int seg = -1;
        for (int s = 255; s >= 0; --s) {
            if (acc + partial[s] >= (unsigned)TOPK) { seg = s; break; }
            acc += partial[s];
        }
        int bucket = 6144;
        if (seg >= 0) {
            for (int b = seg * 8 + 7; b >= seg * 8; --b) {
                acc += hist[b];
                if (acc >= (unsigned)TOPK) { bucket = 6144 + b; break; }
            }
        }
        float lo = key_unmap(((unsigned)bucket) << 19) - 2.0f * EPS;
        sh_tk = key_map(lo);
    }
    __syncthreads();

    const unsigned TK = sh_tk;
    u64* erow = emit + (size_t)grow * CAP;
    for (int i = t * 4; i < S_DIM; i += 1024) {
        float4 v = *(const float4*)(prow + i);
        unsigned k[4] = {key_map(v.x), key_map(v.y), key_map(v.z), key_map(v.w)};
#pragma unroll
        for (int j = 0; j < 4; ++j)
            if (k[j] >= TK) {
                int p = atomicAdd(&cnt, 1);
                if (p < CAP) erow[p] = ((u64)k[j] << 32) | (unsigned)(i + j);
            }
    }
    __syncthreads();
    if (t == 0) ccnt[grow] = (cnt < CAP) ? cnt : CAP;
}

__global__ __launch_bounds__(256) void fb_rescore_kernel(
    const float* __restrict__ x, const float* __restrict__ WT,
    const float* __restrict__ benc, const u64* __restrict__ emit,
    const int* __restrict__ ccnt, float* __restrict__ resc,
    const int* __restrict__ flag, int row0)
{
    const int row = row0 + blockIdx.x;
    if (!flag[row]) return;
    const int t = threadIdx.x;
    const int w = t >> 6, l = t & 63;
    int cnt = ccnt[row]; if (cnt > CAP) cnt = CAP;

    __shared__ float xs[K_DIM];
    const float* xr = x + (size_t)row * K_DIM;
    for (int i = t * 4; i < K_DIM; i += 1024)
        *(float4*)&xs[i] = *(const float4*)&xr[i];
    __syncthreads();

    for (int c = w; c < cnt; c += 4) {
        const int s = (int)(emit[(size_t)row * CAP + c] & 0xFFFFFFFFu);
        const float* wc = WT + (size_t)s * K_DIM;
        float acc = 0.f;
#pragma unroll
        for (int j = 0; j < 32; ++j)
            acc = fmaf(xs[l + 64 * j], wc[l + 64 * j], acc);
#pragma unroll
        for (int d = 1; d < 64; d <<= 1) acc += __shfl_xor(acc, d);
        if (l == 0) resc[(size_t)row * CAP + c] = acc + benc[s];
    }
}

__global__ __launch_bounds__(64) void fb_select_kernel(
    const float* __restrict__ resc, const u64* __restrict__ emit,
    const int* __restrict__ ccnt, float* __restrict__ tv,
    int* __restrict__ ti, const int* __restrict__ flag, int row0)
{
    const int row = row0 + blockIdx.x;
    if (!flag[row]) return;
    const int l = threadIdx.x;
    int cnt = ccnt[row]; if (cnt > CAP) cnt = CAP;

    float v[4] = {0.f, 0.f, 0.f, 0.f};
    int   s[4] = {-1, -1, -1, -1};
    u64   p[4] = {0, 0, 0, 0};
#pragma unroll
    for (int j = 0; j < 4; ++j) {
        int c = l + j * 64;
        if (c < cnt) {
            s[j] = (int)(emit[(size_t)row * CAP + c] & 0xFFFFFFFFu);
            v[j] = resc[(size_t)row * CAP + c];
            p[j] = ((u64)key_map(v[j]) << 32) | (unsigned)(~s[j]);
        }
    }

    float* tvr = tv + (size_t)row * TOPK;
    int*   tir = ti + (size_t)row * TOPK;
#pragma unroll 1
    for (int r = 0; r < TOPK; ++r) {
        u64 m = p[0];
        if (p[1] > m) m = p[1];
        if (p[2] > m) m = p[2];
        if (p[3] > m) m = p[3];
#pragma unroll
        for (int d = 1; d < 64; d <<= 1) {
            u64 o = __shfl_xor(m, d);
            if (o > m) m = o;
        }
        if (p[0] == m)      { tvr[r] = v[0]; tir[r] = s[0] < 0 ? 0 : s[0]; p[0] = 0; }
        else if (p[1] == m) { tvr[r] = v[1]; tir[r] = s[1] < 0 ? 0 : s[1]; p[1] = 0; }
        else if (p[2] == m) { tvr[r] = v[2]; tir[r] = s[2] < 0 ? 0 : s[2]; p[2] = 0; }
        else if (p[3] == m) { tvr[r] = v[3]; tir[r] = s[3] < 0 ? 0 : s[3]; p[3] = 0; }
    }
}

// ---------------------------------------------------------------------------
// Decode (verified): out[row] = b_dec + sum relu(tv)*W_dec[ti]
// ---------------------------------------------------------------------------
__global__ __launch_bounds__(256) void decode_kernel(
    const float* __restrict__ tval, const int* __restrict__ tidx,
    const float* __restrict__ Wd, const float* __restrict__ bdec,
    float* __restrict__ out, int row0)
{
    const int row = row0 + blockIdx.x;
    const int t = threadIdx.x;
    __shared__ float sv[TOPK];
    __shared__ int   si[TOPK];
    if (t < TOPK) {
        sv[t] = fmaxf(tval[(size_t)row * TOPK + t], 0.f);
        si[t] = tidx[(size_t)row * TOPK + t];
    }
    __syncthreads();

    const int c0 = t * 4;
    float4 acc0 = *(const float4*)(bdec + c0);
    float4 acc1 = *(const float4*)(bdec + 1024 + c0);
#pragma unroll 4
    for (int i = 0; i < TOPK; ++i) {
        const float z = sv[i];
        if (z > 0.f) {
            const float* wr = Wd + (size_t)si[i] * K_DIM;
            float4 w0 = *(const float4*)(wr + c0);
            float4 w1 = *(const float4*)(wr + 1024 + c0);
            acc0.x = fmaf(z, w0.x, acc0.x); acc0.y = fmaf(z, w0.y, acc0.y);
            acc0.z = fmaf(z, w0.z, acc0.z); acc0.w = fmaf(z, w0.w, acc0.w);
            acc1.x = fmaf(z, w1.x, acc1.x); acc1.y = fmaf(z, w1.y, acc1.y);
            acc1.z = fmaf(z, w1.z, acc1.z); acc1.w = fmaf(z, w1.w, acc1.w);
        }
    }
    float* op = out + (size_t)row * K_DIM;
    *(float4*)(op + c0) = acc0;
    *(float4*)(op + 1024 + c0) = acc1;
}

// ---------------------------------------------------------------------------
extern "C" void kernel_launch(void* const* d_in, const int* in_sizes, int n_in,
                              void* d_out, int out_size, void* d_ws, size_t ws_size,
                              hipStream_t stream)
{
    const float* x     = (const float*)d_in[0];
    const float* W_enc = (const float*)d_in[1];
    const float* W_dec = (const float*)d_in[2];
    const float* b_enc = (const float*)d_in[3];
    const float* b_dec = (const float*)d_in[4];
    float* out = (float*)d_out;

    const int M = in_sizes[0] / K_DIM;   // 4096 batch rows

    // ws layout: tv | ti | emit | ccnt | thrv | flag | hist | resc | Xh | Wh | WT | pre
    char* wsb = (char*)d_ws;
    size_t o = 0;
    float*    tv   = (float*)(wsb + o);    o += (size_t)M * TOPK * 4;
    int*      ti   = (int*)(wsb + o);      o += (size_t)M * TOPK * 4;
    u64*      emit = (u64*)(wsb + o);      o += (size_t)M * CAP * 8;
    int*      ccnt = (int*)(wsb + o);      o += (size_t)M * 4;
    float*    thrv = (float*)(wsb + o);    o += (size_t)M * 4;
    int*      flag = (int*)(wsb + o);      o += (size_t)M * 4;
    unsigned* hist = (unsigned*)(wsb + o); o += (size_t)M * 64 * 4;
    float*    resc = (float*)(wsb + o);    o += (size_t)M * CAP * 4;
    u16*      Xh   = (u16*)(wsb + o);      o += (size_t)M * K_DIM * 2;
    u16*      Wh   = (u16*)(wsb + o);      o += (size_t)S_DIM * K_DIM * 2;
    float*    WT   = (float*)(wsb + o);    o += (size_t)S_DIM * K_DIM * 4;
    float*    pre  = (float*)(wsb + o);

    size_t cap = (ws_size > o) ? (ws_size - o) : 0;
    long cap_rows = (long)(cap / ((size_t)S_DIM * 4));
    int chunk = (int)((cap_rows / 256) * 256);
    if (chunk <= 0) chunk = 256;
    if (chunk > M) chunk = M;

    init_kernel<<<1024, 256, 0, stream>>>(ccnt, flag, hist, M);
    const int n4 = M * K_DIM / 4;
    conv_x_kernel<<<(n4 + 255) / 256, 256, 0, stream>>>(x, Xh, n4);
    conv_wt_kernel<<<dim3(S_DIM / 64, K_DIM / 64), 256, 0, stream>>>(W_enc, WT, Wh);

    for (int r0 = 0; r0 < M; r0 += chunk) {
        const int rows = (M - r0 < chunk) ? (M - r0) : chunk;
        const int nbm = rows / 256;
        gemm_mfma_kernel<<<nbm * 128, 512, 0, stream>>>(
            Xh + (size_t)r0 * K_DIM, Wh, b_enc, pre, emit, ccnt, hist, r0);
        thr_kernel<<<rows / 64, 64, 0, stream>>>(hist, ccnt, thrv, flag, r0);
        rescore_kernel<<<rows, 256, 0, stream>>>(x, WT, b_enc, emit, ccnt, thrv, resc, r0);
        select_kernel<<<rows, 64, 0, stream>>>(resc, emit, ccnt, thrv, tv, ti, flag, r0);
        fb_screen_kernel<<<rows, 256, 0, stream>>>(pre, emit, ccnt, flag, r0);
        fb_rescore_kernel<<<rows, 256, 0, stream>>>(x, WT, b_enc, emit, ccnt, resc, flag, r0);
        fb_select_kernel<<<rows, 64, 0, stream>>>(resc, emit, ccnt, tv, ti, flag, r0);
        decode_kernel<<<rows, 256, 0, stream>>>(tv, ti, W_dec, b_dec, out, r0);
    }
}

// Round 7
// 1295.053 us; speedup vs baseline: 1.1736x; 1.1736x over previous
//
#include <hip/hip_runtime.h>
#include <cstdint>
#include <cstddef>

typedef unsigned short u16;
typedef unsigned long long u64;
typedef __attribute__((ext_vector_type(8))) short short8;   // 8 x bf16 fragment
typedef __attribute__((ext_vector_type(4))) float f32x4;    // MFMA accumulator

constexpr int K_DIM = 2048;    // N_POS * D_MODEL (contraction dim for encode)
constexpr int S_DIM = 32768;   // D_SAE
constexpr int TOPK  = 32;
constexpr int CAP   = 256;     // max candidates per row (4 x 64 lanes in select)
#define EPS      0.06f         // bf16-GEMM max error bound (13 sigma, r3-r6 proven)
#define THR_EMIT 3.7f          // collect floor (needs v32a >= 3.82; 7-sigma safe)
#define HIST_LO  3.5f          // histogram floor, 64 buckets of width 0.04

// ---------------------------------------------------------------------------
__device__ __forceinline__ u16 f2bf(float f) {
    unsigned u = __float_as_uint(f);
    return (u16)((u + 0x7FFFu + ((u >> 16) & 1u)) >> 16);
}
__device__ __forceinline__ unsigned key_map(float f) {
    unsigned u = __float_as_uint(f);
    return (u & 0x80000000u) ? ~u : (u | 0x80000000u);
}
__device__ __forceinline__ float key_unmap(unsigned k) {
    unsigned u = (k & 0x80000000u) ? (k ^ 0x80000000u) : ~k;
    return __uint_as_float(u);
}

__global__ __launch_bounds__(256) void init_kernel(int* __restrict__ flag, int M)
{
    int i = blockIdx.x * 256 + threadIdx.x;
    if (i < M) flag[i] = 0;
}

// x fp32 -> bf16 (for MFMA screening)
__global__ __launch_bounds__(256) void conv_x_kernel(
    const float* __restrict__ x, u16* __restrict__ hi, int n4)
{
    int i = blockIdx.x * 256 + threadIdx.x;
    if (i >= n4) return;
    float4 v = ((const float4*)x)[i];
    ushort4 h;
    h.x = f2bf(v.x); h.y = f2bf(v.y); h.z = f2bf(v.z); h.w = f2bf(v.w);
    ((ushort4*)hi)[i] = h;
}

// W_enc [K][S] f32 -> WT [S][K] f32 (exact, for rescoring) + Wh [S][K] bf16.
__global__ __launch_bounds__(256) void conv_wt_kernel(
    const float* __restrict__ W, float* __restrict__ WT, u16* __restrict__ Wh)
{
    __shared__ float tile[64][65];
    const int t  = threadIdx.x;
    const int s0 = blockIdx.x * 64;
    const int k0 = blockIdx.y * 64;
#pragma unroll
    for (int i = 0; i < 4; ++i) {
        int kl = (t >> 4) + i * 16;
        int sc = (t & 15) * 4;
        float4 v = *(const float4*)&W[(size_t)(k0 + kl) * S_DIM + s0 + sc];
        tile[kl][sc] = v.x; tile[kl][sc + 1] = v.y;
        tile[kl][sc + 2] = v.z; tile[kl][sc + 3] = v.w;
    }
    __syncthreads();
    const int klc = (t & 7) * 8;
#pragma unroll
    for (int i = 0; i < 2; ++i) {
        int sl = (t >> 3) + i * 32;
        float f[8];
        short8 h8;
#pragma unroll
        for (int j = 0; j < 8; ++j) {
            f[j] = tile[klc + j][sl];
            h8[j] = (short)f2bf(f[j]);
        }
        size_t o = (size_t)(s0 + sl) * K_DIM + k0 + klc;
        *(float4*)&WT[o]     = make_float4(f[0], f[1], f[2], f[3]);
        *(float4*)&WT[o + 4] = make_float4(f[4], f[5], f[6], f[7]);
        *(short8*)&Wh[o] = h8;
    }
}

// ---------------------------------------------------------------------------
// Screening GEMM, 256x256 8-phase schedule — EXACT r5 kernel (verified,
// 630 us, MfmaUtil 38%). Pure stores in epilogue; no atomics (r6 lesson).
// ---------------------------------------------------------------------------
__device__ __forceinline__ void gl16(const u16* g, u16* s) {
    __builtin_amdgcn_global_load_lds(
        (const __attribute__((address_space(1))) unsigned int*)g,
        (__attribute__((address_space(3))) unsigned int*)s,
        16, 0, 0);
}

#define LGKM0  do { asm volatile("s_waitcnt lgkmcnt(0)" ::: "memory"); \
                    __builtin_amdgcn_sched_barrier(0); } while (0)
#define VMW(n) asm volatile("s_waitcnt vmcnt(" #n ")" ::: "memory")
#define BAR    do { __builtin_amdgcn_s_barrier(); \
                    __builtin_amdgcn_sched_barrier(0); } while (0)

__global__ __launch_bounds__(512, 2) void gemm_mfma_kernel(
    const u16* __restrict__ A, const u16* __restrict__ B,
    const float* __restrict__ bias, float* __restrict__ C)
{
    __shared__ alignas(16) u16 sA[2][256 * 64];
    __shared__ alignas(16) u16 sB[2][256 * 64];

    const int t = threadIdx.x;
    const int lane = t & 63;
    const int w = t >> 6;
    const int wm = w >> 2, wn = w & 3;

    const int nwg = gridDim.x;
    const int q = nwg >> 3;
    const int bid = blockIdx.x;
    const int wg = (bid & 7) * q + (bid >> 3);
    const int bm = wg >> 7;
    const int bn = wg & 127;

    const u16* Ab = A + (size_t)bm * 256 * K_DIM;
    const u16* Bb = B + (size_t)bn * 256 * K_DIM;

    const int w2  = w * 2;
    const int lr3 = lane >> 3;
    const int csw = ((lane & 7) ^ lr3) * 8;

    const int rl = lane & 15, kq = lane >> 4;
    const int swz = rl & 7;
    const int ac0 = (kq ^ swz) * 8;
    const int ac1 = ((4 + kq) ^ swz) * 8;
    const int arow = (wm * 16 + rl) * 64;
    const int brow = (wn * 16 + rl) * 64;

    f32x4 acc[8][4];
#pragma unroll
    for (int m = 0; m < 8; ++m)
#pragma unroll
        for (int n = 0; n < 4; ++n) acc[m][n] = (f32x4){0.f, 0.f, 0.f, 0.f};

    auto stA = [&](int half, int j, int kt, int buf) {
        const u16* src = Ab + (size_t)(half * 128 + (w2 + j) * 8 + lr3) * K_DIM
                            + kt * 64 + csw;
        gl16(src, &sA[buf][half * 8192 + (w2 + j) * 512]);
    };
    auto stB = [&](int half, int j, int kt, int buf) {
        const u16* src = Bb + (size_t)(half * 128 + (w2 + j) * 8 + lr3) * K_DIM
                            + kt * 64 + csw;
        gl16(src, &sB[buf][half * 8192 + (w2 + j) * 512]);
    };

    stA(0, 0, 0, 0); stA(0, 1, 0, 0);
    stB(0, 0, 0, 0); stB(0, 1, 0, 0);
    stB(1, 0, 0, 0); stB(1, 1, 0, 0);
    stA(1, 0, 0, 0); stA(1, 1, 0, 0);
    VMW(4);
    BAR;

    short8 af[4][2], bf[4][2];

#pragma unroll 1
    for (int kt = 0; kt < 32; ++kt) {
        const int cur = kt & 1, nxt = cur ^ 1;
        const bool more = (kt < 31);

        // ---- P1
#pragma unroll
        for (int m = 0; m < 4; ++m) {
            af[m][0] = *(const short8*)&sA[cur][arow + m * 2048 + ac0];
            af[m][1] = *(const short8*)&sA[cur][arow + m * 2048 + ac1];
        }
#pragma unroll
        for (int n = 0; n < 2; ++n) {
            bf[n][0] = *(const short8*)&sB[cur][brow + n * 4096 + ac0];
            bf[n][1] = *(const short8*)&sB[cur][brow + n * 4096 + ac1];
        }
        if (more) { stA(0, 0, kt + 1, nxt); stA(0, 1, kt + 1, nxt); }
        __builtin_amdgcn_s_barrier();
        LGKM0;
        __builtin_amdgcn_s_setprio(1);
#pragma unroll
        for (int m = 0; m < 4; ++m)
#pragma unroll
            for (int n = 0; n < 2; ++n)
#pragma unroll
                for (int kk = 0; kk < 2; ++kk)
                    acc[m][n] = __builtin_amdgcn_mfma_f32_16x16x32_bf16(
                        af[m][kk], bf[n][kk], acc[m][n], 0, 0, 0);
        __builtin_amdgcn_s_setprio(0);
        if (more) VMW(4); else VMW(2);
        BAR;

        // ---- P2
#pragma unroll
        for (int n = 2; n < 4; ++n) {
            bf[n][0] = *(const short8*)&sB[cur][brow + n * 4096 + ac0];
            bf[n][1] = *(const short8*)&sB[cur][brow + n * 4096 + ac1];
        }
        if (more) { stB(0, 0, kt + 1, nxt); stB(0, 1, kt + 1, nxt); }
        __builtin_amdgcn_s_barrier();
        LGKM0;
        __builtin_amdgcn_s_setprio(1);
#pragma unroll
        for (int m = 0; m < 4; ++m)
#pragma unroll
            for (int n = 2; n < 4; ++n)
#pragma unroll
                for (int kk = 0; kk < 2; ++kk)
                    acc[m][n] = __builtin_amdgcn_mfma_f32_16x16x32_bf16(
                        af[m][kk], bf[n][kk], acc[m][n], 0, 0, 0);
        __builtin_amdgcn_s_setprio(0);
        if (more) VMW(4); else VMW(0);
        BAR;

        // ---- P3
#pragma unroll
        for (int m = 0; m < 4; ++m) {
            af[m][0] = *(const short8*)&sA[cur][arow + (m + 4) * 2048 + ac0];
            af[m][1] = *(const short8*)&sA[cur][arow + (m + 4) * 2048 + ac1];
        }
        if (more) { stB(1, 0, kt + 1, nxt); stB(1, 1, kt + 1, nxt); }
        __builtin_amdgcn_s_barrier();
        LGKM0;
        __builtin_amdgcn_s_setprio(1);
#pragma unroll
        for (int m = 0; m < 4; ++m)
#pragma unroll
            for (int n = 2; n < 4; ++n)
#pragma unroll
                for (int kk = 0; kk < 2; ++kk)
                    acc[m + 4][n] = __builtin_amdgcn_mfma_f32_16x16x32_bf16(
                        af[m][kk], bf[n][kk], acc[m + 4][n], 0, 0, 0);
        __builtin_amdgcn_s_setprio(0);
        BAR;

        // ---- P4
        if (more) { stA(1, 0, kt + 1, nxt); stA(1, 1, kt + 1, nxt); }
        __builtin_amdgcn_s_barrier();
        __builtin_amdgcn_s_setprio(1);
#pragma unroll
        for (int m = 0; m < 4; ++m)
#pragma unroll
            for (int n = 0; n < 2; ++n)
#pragma unroll
                for (int kk = 0; kk < 2; ++kk)
                    acc[m + 4][n] = __builtin_amdgcn_mfma_f32_16x16x32_bf16(
                        af[m][kk], bf[n][kk], acc[m + 4][n], 0, 0, 0);
        __builtin_amdgcn_s_setprio(0);
        if (more) VMW(4);
        BAR;
    }

    // epilogue: C/D layout col = lane&15, row = (lane>>4)*4 + reg
    const int colB = bn * 256 + wn * 16 + rl;
    const size_t rowB = (size_t)bm * 256 + wm * 16 + kq * 4;
    float bv[4];
#pragma unroll
    for (int n = 0; n < 4; ++n) bv[n] = bias[colB + n * 64];
#pragma unroll
    for (int m = 0; m < 8; ++m)
#pragma unroll
        for (int n = 0; n < 4; ++n)
#pragma unroll
            for (int rr = 0; rr < 4; ++rr)
                C[(rowB + m * 32 + rr) * S_DIM + colB + n * 64] =
                    acc[m][n][rr] + bv[n];
}

// ---------------------------------------------------------------------------
// Screen v3: SINGLE pass over pre. Per-row block: 64-bucket LDS histogram
// (v >= 3.5, width 0.04) + collect (v >= 3.7) as packed (key<<32|col), then
// in-kernel suffix scan -> refined threshold thr = bucket_lo(32nd) - 2*EPS.
// Guarantee: bucket_lo <= v32a, so {approx >= thr} superset of true top-32
// under |approx-exact|<=EPS. Flags rows where thr < collect floor (7-sigma
// tail) or CAP overflow -> exact fallback path.
// ---------------------------------------------------------------------------
__global__ __launch_bounds__(256) void screen_kernel(
    const float* __restrict__ pre, u64* __restrict__ emit,
    int* __restrict__ ccnt, float* __restrict__ thrv,
    int* __restrict__ flag, int row0)
{
    __shared__ unsigned hist[64];
    __shared__ int cnt;

    const int t = threadIdx.x;
    const int row = blockIdx.x;           // chunk-local
    const int grow = row0 + row;
    const float* prow = pre + (size_t)row * S_DIM;

    if (t < 64) hist[t] = 0;
    if (t == 0) cnt = 0;
    __syncthreads();

    u64* erow = emit + (size_t)grow * CAP;
    for (int i = t * 4; i < S_DIM; i += 1024) {
        float4 v = *(const float4*)(prow + i);
        float vv[4] = {v.x, v.y, v.z, v.w};
#pragma unroll
        for (int j = 0; j < 4; ++j) {
            if (vv[j] >= HIST_LO) {
                int b = (int)((vv[j] - HIST_LO) * 25.0f);
                if (b > 63) b = 63;
                atomicAdd(&hist[b], 1u);
                if (vv[j] >= THR_EMIT) {
                    int p = atomicAdd(&cnt, 1);
                    if (p < CAP)
                        erow[p] = ((u64)key_map(vv[j]) << 32) | (unsigned)(i + j);
                }
            }
        }
    }
    __syncthreads();

    if (t == 0) {
        unsigned acc = 0;
        int b = -1;
        for (int j = 63; j >= 0; --j) {
            acc += hist[j];
            if (acc >= (unsigned)TOPK) { b = j; break; }
        }
        float thr = HIST_LO + 0.04f * b - 2.0f * EPS - 1e-4f;
        if (b < 0 || cnt > CAP || thr < THR_EMIT) {
            flag[grow] = 1;
            thr = THR_EMIT;
        }
        thrv[grow] = thr;
        ccnt[grow] = (cnt < CAP) ? cnt : CAP;
    }
}

// ---------------------------------------------------------------------------
// Rescore: exact fp32 dot for candidates passing the refined threshold.
// (summation order identical to r3-r6 — bitwise-stable across rounds)
// ---------------------------------------------------------------------------
__global__ __launch_bounds__(256) void rescore_kernel(
    const float* __restrict__ x, const float* __restrict__ WT,
    const float* __restrict__ benc, const u64* __restrict__ emit,
    const int* __restrict__ ccnt, const float* __restrict__ thrv,
    float* __restrict__ resc, int row0)
{
    const int row = row0 + blockIdx.x;
    const int t = threadIdx.x;
    const int w = t >> 6, l = t & 63;
    const int cnt = ccnt[row];
    const float thr = thrv[row];

    __shared__ float xs[K_DIM];
    const float* xr = x + (size_t)row * K_DIM;
    for (int i = t * 4; i < K_DIM; i += 1024)
        *(float4*)&xs[i] = *(const float4*)&xr[i];
    __syncthreads();

    for (int c = w; c < cnt; c += 4) {
        const u64 pk = emit[(size_t)row * CAP + c];
        const float approx = key_unmap((unsigned)(pk >> 32));
        if (approx < thr) {
            if (l == 0) resc[(size_t)row * CAP + c] = -3e38f;
            continue;
        }
        const int s = (int)(pk & 0xFFFFFFFFu);
        const float* wc = WT + (size_t)s * K_DIM;
        float acc = 0.f;
#pragma unroll
        for (int j = 0; j < 32; ++j)
            acc = fmaf(xs[l + 64 * j], wc[l + 64 * j], acc);
#pragma unroll
        for (int d = 1; d < 64; d <<= 1) acc += __shfl_xor(acc, d);
        if (l == 0) resc[(size_t)row * CAP + c] = acc + benc[s];
    }
}

// ---------------------------------------------------------------------------
// Select: exact top-32 (value desc, index asc) + exactness validation:
//   v32_rescored >= thr + EPS proves no below-threshold item can be top-32.
// ---------------------------------------------------------------------------
__global__ __launch_bounds__(64) void select_kernel(
    const float* __restrict__ resc, const u64* __restrict__ emit,
    const int* __restrict__ ccnt, const float* __restrict__ thrv,
    float* __restrict__ tv, int* __restrict__ ti, int* __restrict__ flag,
    int row0)
{
    const int row = row0 + blockIdx.x;
    const int l = threadIdx.x;
    const int cnt = ccnt[row];

    float v[4] = {0.f, 0.f, 0.f, 0.f};
    int   s[4] = {-1, -1, -1, -1};
    u64   p[4] = {0, 0, 0, 0};
#pragma unroll
    for (int j = 0; j < 4; ++j) {
        int c = l + j * 64;
        if (c < cnt) {
            s[j] = (int)(emit[(size_t)row * CAP + c] & 0xFFFFFFFFu);
            v[j] = resc[(size_t)row * CAP + c];
            p[j] = ((u64)key_map(v[j]) << 32) | (unsigned)(~s[j]);
        }
    }

    float* tvr = tv + (size_t)row * TOPK;
    int*   tir = ti + (size_t)row * TOPK;
    float v32f = -3e38f;
#pragma unroll 1
    for (int r = 0; r < TOPK; ++r) {
        u64 m = p[0];
        if (p[1] > m) m = p[1];
        if (p[2] > m) m = p[2];
        if (p[3] > m) m = p[3];
#pragma unroll
        for (int d = 1; d < 64; d <<= 1) {
            u64 o = __shfl_xor(m, d);
            if (o > m) m = o;
        }
        if (r == TOPK - 1) v32f = key_unmap((unsigned)(m >> 32));
        if (p[0] == m)      { tvr[r] = v[0]; tir[r] = s[0] < 0 ? 0 : s[0]; p[0] = 0; }
        else if (p[1] == m) { tvr[r] = v[1]; tir[r] = s[1] < 0 ? 0 : s[1]; p[1] = 0; }
        else if (p[2] == m) { tvr[r] = v[2]; tir[r] = s[2] < 0 ? 0 : s[2]; p[2] = 0; }
        else if (p[3] == m) { tvr[r] = v[3]; tir[r] = s[3] < 0 ? 0 : s[3]; p[3] = 0; }
    }
    if (l == 0) {
        if (v32f < thrv[row] + EPS) flag[row] = 1;
    }
}

// ---------------------------------------------------------------------------
// Fallback (flag-guarded, normally 0 active rows): r4-verified exact
// fine-histogram screen over the pre row, then rescore + select.
// ---------------------------------------------------------------------------
__global__ __launch_bounds__(256) void fb_screen_kernel(
    const float* __restrict__ pre, u64* __restrict__ emit,
    int* __restrict__ ccnt, const int* __restrict__ flag, int row0)
{
    const int grow = row0 + blockIdx.x;
    if (!flag[grow]) return;

    __shared__ unsigned hist[2048];
    __shared__ unsigned partial[256];
    __shared__ unsigned sh_tk;
    __shared__ int cnt;

    const int t = threadIdx.x;
    const float* prow = pre + (size_t)blockIdx.x * S_DIM;

    for (int i = t; i < 2048; i += 256) hist[i] = 0;
    if (t == 0) cnt = 0;
    __syncthreads();

    for (int i = t * 4; i < S_DIM; i += 1024) {
        float4 v = *(const float4*)(prow + i);
        unsigned k0 = key_map(v.x), k1 = key_map(v.y),
                 k2 = key_map(v.z), k3 = key_map(v.w);
        if (k0 >= 0xC0000000u) atomicAdd(&hist[(k0 >> 19) - 6144], 1u);
        if (k1 >= 0xC0000000u) atomicAdd(&hist[(k1 >> 19) - 6144], 1u);
        if (k2 >= 0xC0000000u) atomicAdd(&hist[(k2 >> 19) - 6144], 1u);
        if (k3 >= 0xC0000000u) atomicAdd(&hist[(k3 >> 19) - 6144], 1u);
    }
    __syncthreads();

    unsigned ps = 0;
#pragma unroll
    for (int j = 0; j < 8; ++j) ps += hist[t * 8 + j];
    partial[t] = ps;
    __syncthreads();

    if (t == 0) {
        unsigned acc = 0;
        int seg = -1;
        for (int s = 255; s >= 0; --s) {
            if (acc + partial[s] >= (unsigned)TOPK) { seg = s; break; }
            acc += partial[s];
        }
        int bucket = 6144;
        if (seg >= 0) {
            for (int b = seg * 8 + 7; b >= seg * 8; --b) {
                acc += hist[b];
                if (acc >= (unsigned)TOPK) { bucket = 6144 + b; break; }
            }
        }
        float lo = key_unmap(((unsigned)bucket) << 19) - 2.0f * EPS;
        sh_tk = key_map(lo);
    }
    __syncthreads();

    const unsigned TK = sh_tk;
    u64* erow = emit + (size_t)grow * CAP;
    for (int i = t * 4; i < S_DIM; i += 1024) {
        float4 v = *(const float4*)(prow + i);
        unsigned k[4] = {key_map(v.x), key_map(v.y), key_map(v.z), key_map(v.w)};
#pragma unroll
        for (int j = 0; j < 4; ++j)
            if (k[j] >= TK) {
                int p = atomicAdd(&cnt, 1);
                if (p < CAP) erow[p] = ((u64)k[j] << 32) | (unsigned)(i + j);
            }
    }
    __syncthreads();
    if (t == 0) ccnt[grow] = (cnt < CAP) ? cnt : CAP;
}

__global__ __launch_bounds__(256) void fb_rescore_kernel(
    const float* __restrict__ x, const float* __restrict__ WT,
    const float* __restrict__ benc, const u64* __restrict__ emit,
    const int* __restrict__ ccnt, float* __restrict__ resc,
    const int* __restrict__ flag, int row0)
{
    const int row = row0 + blockIdx.x;
    if (!flag[row]) return;
    const int t = threadIdx.x;
    const int w = t >> 6, l = t & 63;
    const int cnt = ccnt[row];

    __shared__ float xs[K_DIM];
    const float* xr = x + (size_t)row * K_DIM;
    for (int i = t * 4; i < K_DIM; i += 1024)
        *(float4*)&xs[i] = *(const float4*)&xr[i];
    __syncthreads();

    for (int c = w; c < cnt; c += 4) {
        const int s = (int)(emit[(size_t)row * CAP + c] & 0xFFFFFFFFu);
        const float* wc = WT + (size_t)s * K_DIM;
        float acc = 0.f;
#pragma unroll
        for (int j = 0; j < 32; ++j)
            acc = fmaf(xs[l + 64 * j], wc[l + 64 * j], acc);
#pragma unroll
        for (int d = 1; d < 64; d <<= 1) acc += __shfl_xor(acc, d);
        if (l == 0) resc[(size_t)row * CAP + c] = acc + benc[s];
    }
}

__global__ __launch_bounds__(64) void fb_select_kernel(
    const float* __restrict__ resc, const u64* __restrict__ emit,
    const int* __restrict__ ccnt, float* __restrict__ tv,
    int* __restrict__ ti, const int* __restrict__ flag, int row0)
{
    const int row = row0 + blockIdx.x;
    if (!flag[row]) return;
    const int l = threadIdx.x;
    const int cnt = ccnt[row];

    float v[4] = {0.f, 0.f, 0.f, 0.f};
    int   s[4] = {-1, -1, -1, -1};
    u64   p[4] = {0, 0, 0, 0};
#pragma unroll
    for (int j = 0; j < 4; ++j) {
        int c = l + j * 64;
        if (c < cnt) {
            s[j] = (int)(emit[(size_t)row * CAP + c] & 0xFFFFFFFFu);
            v[j] = resc[(size_t)row * CAP + c];
            p[j] = ((u64)key_map(v[j]) << 32) | (unsigned)(~s[j]);
        }
    }

    float* tvr = tv + (size_t)row * TOPK;
    int*   tir = ti + (size_t)row * TOPK;
#pragma unroll 1
    for (int r = 0; r < TOPK; ++r) {
        u64 m = p[0];
        if (p[1] > m) m = p[1];
        if (p[2] > m) m = p[2];
        if (p[3] > m) m = p[3];
#pragma unroll
        for (int d = 1; d < 64; d <<= 1) {
            u64 o = __shfl_xor(m, d);
            if (o > m) m = o;
        }
        if (p[0] == m)      { tvr[r] = v[0]; tir[r] = s[0] < 0 ? 0 : s[0]; p[0] = 0; }
        else if (p[1] == m) { tvr[r] = v[1]; tir[r] = s[1] < 0 ? 0 : s[1]; p[1] = 0; }
        else if (p[2] == m) { tvr[r] = v[2]; tir[r] = s[2] < 0 ? 0 : s[2]; p[2] = 0; }
        else if (p[3] == m) { tvr[r] = v[3]; tir[r] = s[3] < 0 ? 0 : s[3]; p[3] = 0; }
    }
}

// ---------------------------------------------------------------------------
// Decode (verified): out[row] = b_dec + sum relu(tv)*W_dec[ti]
// ---------------------------------------------------------------------------
__global__ __launch_bounds__(256) void decode_kernel(
    const float* __restrict__ tval, const int* __restrict__ tidx,
    const float* __restrict__ Wd, const float* __restrict__ bdec,
    float* __restrict__ out, int row0)
{
    const int row = row0 + blockIdx.x;
    const int t = threadIdx.x;
    __shared__ float sv[TOPK];
    __shared__ int   si[TOPK];
    if (t < TOPK) {
        sv[t] = fmaxf(tval[(size_t)row * TOPK + t], 0.f);
        si[t] = tidx[(size_t)row * TOPK + t];
    }
    __syncthreads();

    const int c0 = t * 4;
    float4 acc0 = *(const float4*)(bdec + c0);
    float4 acc1 = *(const float4*)(bdec + 1024 + c0);
#pragma unroll 4
    for (int i = 0; i < TOPK; ++i) {
        const float z = sv[i];
        if (z > 0.f) {
            const float* wr = Wd + (size_t)si[i] * K_DIM;
            float4 w0 = *(const float4*)(wr + c0);
            float4 w1 = *(const float4*)(wr + 1024 + c0);
            acc0.x = fmaf(z, w0.x, acc0.x); acc0.y = fmaf(z, w0.y, acc0.y);
            acc0.z = fmaf(z, w0.z, acc0.z); acc0.w = fmaf(z, w0.w, acc0.w);
            acc1.x = fmaf(z, w1.x, acc1.x); acc1.y = fmaf(z, w1.y, acc1.y);
            acc1.z = fmaf(z, w1.z, acc1.z); acc1.w = fmaf(z, w1.w, acc1.w);
        }
    }
    float* op = out + (size_t)row * K_DIM;
    *(float4*)(op + c0) = acc0;
    *(float4*)(op + 1024 + c0) = acc1;
}

// ---------------------------------------------------------------------------
extern "C" void kernel_launch(void* const* d_in, const int* in_sizes, int n_in,
                              void* d_out, int out_size, void* d_ws, size_t ws_size,
                              hipStream_t stream)
{
    const float* x     = (const float*)d_in[0];
    const float* W_enc = (const float*)d_in[1];
    const float* W_dec = (const float*)d_in[2];
    const float* b_enc = (const float*)d_in[3];
    const float* b_dec = (const float*)d_in[4];
    float* out = (float*)d_out;

    const int M = in_sizes[0] / K_DIM;   // 4096 batch rows

    // ws layout: tv | ti | emit | ccnt | thrv | flag | resc | Xh | Wh | WT | pre
    char* wsb = (char*)d_ws;
    size_t o = 0;
    float*    tv   = (float*)(wsb + o);    o += (size_t)M * TOPK * 4;
    int*      ti   = (int*)(wsb + o);      o += (size_t)M * TOPK * 4;
    u64*      emit = (u64*)(wsb + o);      o += (size_t)M * CAP * 8;
    int*      ccnt = (int*)(wsb + o);      o += (size_t)M * 4;
    float*    thrv = (float*)(wsb + o);    o += (size_t)M * 4;
    int*      flag = (int*)(wsb + o);      o += (size_t)M * 4;
    float*    resc = (float*)(wsb + o);    o += (size_t)M * CAP * 4;
    u16*      Xh   = (u16*)(wsb + o);      o += (size_t)M * K_DIM * 2;
    u16*      Wh   = (u16*)(wsb + o);      o += (size_t)S_DIM * K_DIM * 2;
    float*    WT   = (float*)(wsb + o);    o += (size_t)S_DIM * K_DIM * 4;
    float*    pre  = (float*)(wsb + o);

    size_t cap = (ws_size > o) ? (ws_size - o) : 0;
    long cap_rows = (long)(cap / ((size_t)S_DIM * 4));
    int chunk = (int)((cap_rows / 256) * 256);
    if (chunk <= 0) chunk = 256;
    if (chunk > M) chunk = M;

    init_kernel<<<(M + 255) / 256, 256, 0, stream>>>(flag, M);
    const int n4 = M * K_DIM / 4;
    conv_x_kernel<<<(n4 + 255) / 256, 256, 0, stream>>>(x, Xh, n4);
    conv_wt_kernel<<<dim3(S_DIM / 64, K_DIM / 64), 256, 0, stream>>>(W_enc, WT, Wh);

    for (int r0 = 0; r0 < M; r0 += chunk) {
        const int rows = (M - r0 < chunk) ? (M - r0) : chunk;
        const int nbm = rows / 256;
        gemm_mfma_kernel<<<nbm * 128, 512, 0, stream>>>(
            Xh + (size_t)r0 * K_DIM, Wh, b_enc, pre);
        screen_kernel<<<rows, 256, 0, stream>>>(pre, emit, ccnt, thrv, flag, r0);
        rescore_kernel<<<rows, 256, 0, stream>>>(x, WT, b_enc, emit, ccnt, thrv, resc, r0);
        select_kernel<<<rows, 64, 0, stream>>>(resc, emit, ccnt, thrv, tv, ti, flag, r0);
        fb_screen_kernel<<<rows, 256, 0, stream>>>(pre, emit, ccnt, flag, r0);
        fb_rescore_kernel<<<rows, 256, 0, stream>>>(x, WT, b_enc, emit, ccnt, resc, flag, r0);
        fb_select_kernel<<<rows, 64, 0, stream>>>(resc, emit, ccnt, tv, ti, flag, r0);
        decode_kernel<<<rows, 256, 0, stream>>>(tv, ti, W_dec, b_dec, out, r0);
    }
}

// Round 8
// 1233.942 us; speedup vs baseline: 1.2317x; 1.0495x over previous
//
#include <hip/hip_runtime.h>
#include <cstdint>
#include <cstddef>

typedef unsigned short u16;
typedef unsigned long long u64;
typedef __attribute__((ext_vector_type(8))) short short8;   // 8 x bf16 fragment
typedef __attribute__((ext_vector_type(4))) float f32x4;    // MFMA accumulator

constexpr int K_DIM = 2048;    // N_POS * D_MODEL (contraction dim for encode)
constexpr int S_DIM = 32768;   // D_SAE
constexpr int TOPK  = 32;
constexpr int CAP   = 256;     // max candidates per row (4 x 64 lanes in select)
#define EPS      0.06f         // bf16-GEMM max error bound (13 sigma, r3-r7 proven)
#define THR_EMIT 3.7f          // collect floor (needs v32a >= 3.82; 7-sigma safe)
#define HIST_LO  3.5f          // histogram floor, 64 buckets of width 0.04

// ---------------------------------------------------------------------------
__device__ __forceinline__ u16 f2bf(float f) {
    unsigned u = __float_as_uint(f);
    return (u16)((u + 0x7FFFu + ((u >> 16) & 1u)) >> 16);
}
__device__ __forceinline__ unsigned key_map(float f) {
    unsigned u = __float_as_uint(f);
    return (u & 0x80000000u) ? ~u : (u | 0x80000000u);
}
__device__ __forceinline__ float key_unmap(unsigned k) {
    unsigned u = (k & 0x80000000u) ? (k ^ 0x80000000u) : ~k;
    return __uint_as_float(u);
}

__global__ __launch_bounds__(256) void init_kernel(int* __restrict__ flag, int M)
{
    int i = blockIdx.x * 256 + threadIdx.x;
    if (i < M) flag[i] = 0;
}

// x fp32 -> bf16 (for MFMA screening)
__global__ __launch_bounds__(256) void conv_x_kernel(
    const float* __restrict__ x, u16* __restrict__ hi, int n4)
{
    int i = blockIdx.x * 256 + threadIdx.x;
    if (i >= n4) return;
    float4 v = ((const float4*)x)[i];
    ushort4 h;
    h.x = f2bf(v.x); h.y = f2bf(v.y); h.z = f2bf(v.z); h.w = f2bf(v.w);
    ((ushort4*)hi)[i] = h;
}

// W_enc [K][S] f32 -> WT [S][K] f32 (exact, for rescoring) + Wh [S][K] bf16.
__global__ __launch_bounds__(256) void conv_wt_kernel(
    const float* __restrict__ W, float* __restrict__ WT, u16* __restrict__ Wh)
{
    __shared__ float tile[64][65];
    const int t  = threadIdx.x;
    const int s0 = blockIdx.x * 64;
    const int k0 = blockIdx.y * 64;
#pragma unroll
    for (int i = 0; i < 4; ++i) {
        int kl = (t >> 4) + i * 16;
        int sc = (t & 15) * 4;
        float4 v = *(const float4*)&W[(size_t)(k0 + kl) * S_DIM + s0 + sc];
        tile[kl][sc] = v.x; tile[kl][sc + 1] = v.y;
        tile[kl][sc + 2] = v.z; tile[kl][sc + 3] = v.w;
    }
    __syncthreads();
    const int klc = (t & 7) * 8;
#pragma unroll
    for (int i = 0; i < 2; ++i) {
        int sl = (t >> 3) + i * 32;
        float f[8];
        short8 h8;
#pragma unroll
        for (int j = 0; j < 8; ++j) {
            f[j] = tile[klc + j][sl];
            h8[j] = (short)f2bf(f[j]);
        }
        size_t o = (size_t)(s0 + sl) * K_DIM + k0 + klc;
        *(float4*)&WT[o]     = make_float4(f[0], f[1], f[2], f[3]);
        *(float4*)&WT[o + 4] = make_float4(f[4], f[5], f[6], f[7]);
        *(short8*)&Wh[o] = h8;
    }
}

// ---------------------------------------------------------------------------
// Screening GEMM, 256x256, m201-faithful 8-phase/2-K-tile schedule:
//   stages staggered P1..P8 with stage-to-read distance >= 6 phases
//   (>1100 cyc > 900-cyc HBM latency), ONE vmcnt(6) per K-tile (P4/P8 end).
//   Region safety: each stage targets an LDS region whose last reader
//   finished >=1 barrier earlier (derivation in round-8 notes).
//   Data paths (ds offsets, swizzle, stage lambdas, epilogue) = r5/r7
//   verified bytes.
// ---------------------------------------------------------------------------
__device__ __forceinline__ void gl16(const u16* g, u16* s) {
    __builtin_amdgcn_global_load_lds(
        (const __attribute__((address_space(1))) unsigned int*)g,
        (__attribute__((address_space(3))) unsigned int*)s,
        16, 0, 0);
}

#define LGKM0  do { asm volatile("s_waitcnt lgkmcnt(0)" ::: "memory"); \
                    __builtin_amdgcn_sched_barrier(0); } while (0)
#define VMW(n) asm volatile("s_waitcnt vmcnt(" #n ")" ::: "memory")
#define BAR    do { __builtin_amdgcn_s_barrier(); \
                    __builtin_amdgcn_sched_barrier(0); } while (0)

__global__ __launch_bounds__(512, 2) void gemm_mfma_kernel(
    const u16* __restrict__ A, const u16* __restrict__ B,
    const float* __restrict__ bias, float* __restrict__ C)
{
    __shared__ alignas(16) u16 sA[2][256 * 64];
    __shared__ alignas(16) u16 sB[2][256 * 64];

    const int t = threadIdx.x;
    const int lane = t & 63;
    const int w = t >> 6;
    const int wm = w >> 2, wn = w & 3;

    const int nwg = gridDim.x;
    const int q = nwg >> 3;
    const int bid = blockIdx.x;
    const int wg = (bid & 7) * q + (bid >> 3);
    const int bm = wg >> 7;
    const int bn = wg & 127;

    const u16* Ab = A + (size_t)bm * 256 * K_DIM;
    const u16* Bb = B + (size_t)bn * 256 * K_DIM;

    const int w2  = w * 2;
    const int lr3 = lane >> 3;
    const int csw = ((lane & 7) ^ lr3) * 8;

    const int rl = lane & 15, kq = lane >> 4;
    const int swz = rl & 7;
    const int ac0 = (kq ^ swz) * 8;
    const int ac1 = ((4 + kq) ^ swz) * 8;
    const int arow = (wm * 16 + rl) * 64;
    const int brow = (wn * 16 + rl) * 64;

    f32x4 acc[8][4];
#pragma unroll
    for (int m = 0; m < 8; ++m)
#pragma unroll
        for (int n = 0; n < 4; ++n) acc[m][n] = (f32x4){0.f, 0.f, 0.f, 0.f};

    auto stA = [&](int half, int j, int kt, int buf) {
        const u16* src = Ab + (size_t)(half * 128 + (w2 + j) * 8 + lr3) * K_DIM
                            + kt * 64 + csw;
        gl16(src, &sA[buf][half * 8192 + (w2 + j) * 512]);
    };
    auto stB = [&](int half, int j, int kt, int buf) {
        const u16* src = Bb + (size_t)(half * 128 + (w2 + j) * 8 + lr3) * K_DIM
                            + kt * 64 + csw;
        gl16(src, &sB[buf][half * 8192 + (w2 + j) * 512]);
    };

    // Prologue: 7 halves in steady-state FIFO order; drain tile 0 (leave 6).
    stB(0, 0, 0, 0); stB(0, 1, 0, 0);   // Bh0(0)
    stA(0, 0, 0, 0); stA(0, 1, 0, 0);   // Ah0(0)
    stB(1, 0, 0, 0); stB(1, 1, 0, 0);   // Bh1(0)
    stA(1, 0, 0, 0); stA(1, 1, 0, 0);   // Ah1(0)
    stB(0, 0, 1, 1); stB(0, 1, 1, 1);   // Bh0(1)
    stA(0, 0, 1, 1); stA(0, 1, 1, 1);   // Ah0(1)
    stB(1, 0, 1, 1); stB(1, 1, 1, 1);   // Bh1(1)
    VMW(6);
    BAR;

    short8 af[4][2], bf[4][2];

#pragma unroll 1
    for (int it = 0; it < 16; ++it) {
        const bool lastIt = (it == 15);
#pragma unroll
        for (int h = 0; h < 2; ++h) {
            const int b  = h;                  // buffer read this half-iter
            const int tA = 2 * it + 1 + h;     // Ah1 stage tile -> buf b^1
            const int tB = 2 * it + 2 + h;     // Bh0/Ah0/Bh1 stage tile -> buf b

            // ---- ph1: read A m0-3 + B n0-1 (buf b); stage Ah1(tA)
#pragma unroll
            for (int m = 0; m < 4; ++m) {
                af[m][0] = *(const short8*)&sA[b][arow + m * 2048 + ac0];
                af[m][1] = *(const short8*)&sA[b][arow + m * 2048 + ac1];
            }
#pragma unroll
            for (int n = 0; n < 2; ++n) {
                bf[n][0] = *(const short8*)&sB[b][brow + n * 4096 + ac0];
                bf[n][1] = *(const short8*)&sB[b][brow + n * 4096 + ac1];
            }
            if (tA < 32) { stA(1, 0, tA, b ^ 1); stA(1, 1, tA, b ^ 1); }
            __builtin_amdgcn_s_barrier();
            LGKM0;
            __builtin_amdgcn_s_setprio(1);
#pragma unroll
            for (int m = 0; m < 4; ++m)
#pragma unroll
                for (int n = 0; n < 2; ++n)
#pragma unroll
                    for (int kk = 0; kk < 2; ++kk)
                        acc[m][n] = __builtin_amdgcn_mfma_f32_16x16x32_bf16(
                            af[m][kk], bf[n][kk], acc[m][n], 0, 0, 0);
            __builtin_amdgcn_s_setprio(0);
            BAR;

            // ---- ph2: read B n2-3 (buf b); stage Bh0(tB)
#pragma unroll
            for (int n = 2; n < 4; ++n) {
                bf[n][0] = *(const short8*)&sB[b][brow + n * 4096 + ac0];
                bf[n][1] = *(const short8*)&sB[b][brow + n * 4096 + ac1];
            }
            if (tB < 32) { stB(0, 0, tB, b); stB(0, 1, tB, b); }
            __builtin_amdgcn_s_barrier();
            LGKM0;
            __builtin_amdgcn_s_setprio(1);
#pragma unroll
            for (int m = 0; m < 4; ++m)
#pragma unroll
                for (int n = 2; n < 4; ++n)
#pragma unroll
                    for (int kk = 0; kk < 2; ++kk)
                        acc[m][n] = __builtin_amdgcn_mfma_f32_16x16x32_bf16(
                            af[m][kk], bf[n][kk], acc[m][n], 0, 0, 0);
            __builtin_amdgcn_s_setprio(0);
            BAR;

            // ---- ph3: read A m4-7 (buf b); stage Ah0(tB)
#pragma unroll
            for (int m = 0; m < 4; ++m) {
                af[m][0] = *(const short8*)&sA[b][arow + (m + 4) * 2048 + ac0];
                af[m][1] = *(const short8*)&sA[b][arow + (m + 4) * 2048 + ac1];
            }
            if (tB < 32) { stA(0, 0, tB, b); stA(0, 1, tB, b); }
            __builtin_amdgcn_s_barrier();
            LGKM0;
            __builtin_amdgcn_s_setprio(1);
#pragma unroll
            for (int m = 0; m < 4; ++m)
#pragma unroll
                for (int n = 2; n < 4; ++n)
#pragma unroll
                    for (int kk = 0; kk < 2; ++kk)
                        acc[m + 4][n] = __builtin_amdgcn_mfma_f32_16x16x32_bf16(
                            af[m][kk], bf[n][kk], acc[m + 4][n], 0, 0, 0);
            __builtin_amdgcn_s_setprio(0);
            BAR;

            // ---- ph4: no LDS reads; stage Bh1(tB); counted wait
            if (tB < 32) { stB(1, 0, tB, b); stB(1, 1, tB, b); }
            __builtin_amdgcn_s_barrier();
            __builtin_amdgcn_s_setprio(1);
#pragma unroll
            for (int m = 0; m < 4; ++m)
#pragma unroll
                for (int n = 0; n < 2; ++n)
#pragma unroll
                    for (int kk = 0; kk < 2; ++kk)
                        acc[m + 4][n] = __builtin_amdgcn_mfma_f32_16x16x32_bf16(
                            af[m][kk], bf[n][kk], acc[m + 4][n], 0, 0, 0);
            __builtin_amdgcn_s_setprio(0);
            if (lastIt && h == 0) { VMW(0); } else { VMW(6); }
            BAR;
        }
    }

    // epilogue: C/D layout col = lane&15, row = (lane>>4)*4 + reg
    const int colB = bn * 256 + wn * 16 + rl;
    const size_t rowB = (size_t)bm * 256 + wm * 16 + kq * 4;
    float bv[4];
#pragma unroll
    for (int n = 0; n < 4; ++n) bv[n] = bias[colB + n * 64];
#pragma unroll
    for (int m = 0; m < 8; ++m)
#pragma unroll
        for (int n = 0; n < 4; ++n)
#pragma unroll
            for (int rr = 0; rr < 4; ++rr)
                C[(rowB + m * 32 + rr) * S_DIM + colB + n * 64] =
                    acc[m][n][rr] + bv[n];
}

// ---------------------------------------------------------------------------
// Screen v3 (verified r7): single pass, 64-bucket LDS hist + collect +
// in-kernel suffix scan -> refined threshold.
// ---------------------------------------------------------------------------
__global__ __launch_bounds__(256) void screen_kernel(
    const float* __restrict__ pre, u64* __restrict__ emit,
    int* __restrict__ ccnt, float* __restrict__ thrv,
    int* __restrict__ flag, int row0)
{
    __shared__ unsigned hist[64];
    __shared__ int cnt;

    const int t = threadIdx.x;
    const int row = blockIdx.x;           // chunk-local
    const int grow = row0 + row;
    const float* prow = pre + (size_t)row * S_DIM;

    if (t < 64) hist[t] = 0;
    if (t == 0) cnt = 0;
    __syncthreads();

    u64* erow = emit + (size_t)grow * CAP;
    for (int i = t * 4; i < S_DIM; i += 1024) {
        float4 v = *(const float4*)(prow + i);
        float vv[4] = {v.x, v.y, v.z, v.w};
#pragma unroll
        for (int j = 0; j < 4; ++j) {
            if (vv[j] >= HIST_LO) {
                int b = (int)((vv[j] - HIST_LO) * 25.0f);
                if (b > 63) b = 63;
                atomicAdd(&hist[b], 1u);
                if (vv[j] >= THR_EMIT) {
                    int p = atomicAdd(&cnt, 1);
                    if (p < CAP)
                        erow[p] = ((u64)key_map(vv[j]) << 32) | (unsigned)(i + j);
                }
            }
        }
    }
    __syncthreads();

    if (t == 0) {
        unsigned acc = 0;
        int b = -1;
        for (int j = 63; j >= 0; --j) {
            acc += hist[j];
            if (acc >= (unsigned)TOPK) { b = j; break; }
        }
        float thr = HIST_LO + 0.04f * b - 2.0f * EPS - 1e-4f;
        if (b < 0 || cnt > CAP || thr < THR_EMIT) {
            flag[grow] = 1;
            thr = THR_EMIT;
        }
        thrv[grow] = thr;
        ccnt[grow] = (cnt < CAP) ? cnt : CAP;
    }
}

// ---------------------------------------------------------------------------
// Rescore: exact fp32 dot for candidates passing the refined threshold.
// ---------------------------------------------------------------------------
__global__ __launch_bounds__(256) void rescore_kernel(
    const float* __restrict__ x, const float* __restrict__ WT,
    const float* __restrict__ benc, const u64* __restrict__ emit,
    const int* __restrict__ ccnt, const float* __restrict__ thrv,
    float* __restrict__ resc, int row0)
{
    const int row = row0 + blockIdx.x;
    const int t = threadIdx.x;
    const int w = t >> 6, l = t & 63;
    const int cnt = ccnt[row];
    const float thr = thrv[row];

    __shared__ float xs[K_DIM];
    const float* xr = x + (size_t)row * K_DIM;
    for (int i = t * 4; i < K_DIM; i += 1024)
        *(float4*)&xs[i] = *(const float4*)&xr[i];
    __syncthreads();

    for (int c = w; c < cnt; c += 4) {
        const u64 pk = emit[(size_t)row * CAP + c];
        const float approx = key_unmap((unsigned)(pk >> 32));
        if (approx < thr) {
            if (l == 0) resc[(size_t)row * CAP + c] = -3e38f;
            continue;
        }
        const int s = (int)(pk & 0xFFFFFFFFu);
        const float* wc = WT + (size_t)s * K_DIM;
        float acc = 0.f;
#pragma unroll
        for (int j = 0; j < 32; ++j)
            acc = fmaf(xs[l + 64 * j], wc[l + 64 * j], acc);
#pragma unroll
        for (int d = 1; d < 64; d <<= 1) acc += __shfl_xor(acc, d);
        if (l == 0) resc[(size_t)row * CAP + c] = acc + benc[s];
    }
}

// ---------------------------------------------------------------------------
// Select: exact top-32 (value desc, index asc) + exactness validation.
// ---------------------------------------------------------------------------
__global__ __launch_bounds__(64) void select_kernel(
    const float* __restrict__ resc, const u64* __restrict__ emit,
    const int* __restrict__ ccnt, const float* __restrict__ thrv,
    float* __restrict__ tv, int* __restrict__ ti, int* __restrict__ flag,
    int row0)
{
    const int row = row0 + blockIdx.x;
    const int l = threadIdx.x;
    const int cnt = ccnt[row];

    float v[4] = {0.f, 0.f, 0.f, 0.f};
    int   s[4] = {-1, -1, -1, -1};
    u64   p[4] = {0, 0, 0, 0};
#pragma unroll
    for (int j = 0; j < 4; ++j) {
        int c = l + j * 64;
        if (c < cnt) {
            s[j] = (int)(emit[(size_t)row * CAP + c] & 0xFFFFFFFFu);
            v[j] = resc[(size_t)row * CAP + c];
            p[j] = ((u64)key_map(v[j]) << 32) | (unsigned)(~s[j]);
        }
    }

    float* tvr = tv + (size_t)row * TOPK;
    int*   tir = ti + (size_t)row * TOPK;
    float v32f = -3e38f;
#pragma unroll 1
    for (int r = 0; r < TOPK; ++r) {
        u64 m = p[0];
        if (p[1] > m) m = p[1];
        if (p[2] > m) m = p[2];
        if (p[3] > m) m = p[3];
#pragma unroll
        for (int d = 1; d < 64; d <<= 1) {
            u64 o = __shfl_xor(m, d);
            if (o > m) m = o;
        }
        if (r == TOPK - 1) v32f = key_unmap((unsigned)(m >> 32));
        if (p[0] == m)      { tvr[r] = v[0]; tir[r] = s[0] < 0 ? 0 : s[0]; p[0] = 0; }
        else if (p[1] == m) { tvr[r] = v[1]; tir[r] = s[1] < 0 ? 0 : s[1]; p[1] = 0; }
        else if (p[2] == m) { tvr[r] = v[2]; tir[r] = s[2] < 0 ? 0 : s[2]; p[2] = 0; }
        else if (p[3] == m) { tvr[r] = v[3]; tir[r] = s[3] < 0 ? 0 : s[3]; p[3] = 0; }
    }
    if (l == 0) {
        if (v32f < thrv[row] + EPS) flag[row] = 1;
    }
}

// ---------------------------------------------------------------------------
// Fallback (flag-guarded, normally 0 active rows): r4-verified exact
// fine-histogram screen over the pre row, then rescore + select.
// ---------------------------------------------------------------------------
__global__ __launch_bounds__(256) void fb_screen_kernel(
    const float* __restrict__ pre, u64* __restrict__ emit,
    int* __restrict__ ccnt, const int* __restrict__ flag, int row0)
{
    const int grow = row0 + blockIdx.x;
    if (!flag[grow]) return;

    __shared__ unsigned hist[2048];
    __shared__ unsigned partial[256];
    __shared__ unsigned sh_tk;
    __shared__ int cnt;

    const int t = threadIdx.x;
    const float* prow = pre + (size_t)blockIdx.x * S_DIM;

    for (int i = t; i < 2048; i += 256) hist[i] = 0;
    if (t == 0) cnt = 0;
    __syncthreads();

    for (int i = t * 4; i < S_DIM; i += 1024) {
        float4 v = *(const float4*)(prow + i);
        unsigned k0 = key_map(v.x), k1 = key_map(v.y),
                 k2 = key_map(v.z), k3 = key_map(v.w);
        if (k0 >= 0xC0000000u) atomicAdd(&hist[(k0 >> 19) - 6144], 1u);
        if (k1 >= 0xC0000000u) atomicAdd(&hist[(k1 >> 19) - 6144], 1u);
        if (k2 >= 0xC0000000u) atomicAdd(&hist[(k2 >> 19) - 6144], 1u);
        if (k3 >= 0xC0000000u) atomicAdd(&hist[(k3 >> 19) - 6144], 1u);
    }
    __syncthreads();

    unsigned ps = 0;
#pragma unroll
    for (int j = 0; j < 8; ++j) ps += hist[t * 8 + j];
    partial[t] = ps;
    __syncthreads();

    if (t == 0) {
        unsigned acc = 0;
        int seg = -1;
        for (int s = 255; s >= 0; --s) {
            if (acc + partial[s] >= (unsigned)TOPK) { seg = s; break; }
            acc += partial[s];
        }
        int bucket = 6144;
        if (seg >= 0) {
            for (int b = seg * 8 + 7; b >= seg * 8; --b) {
                acc += hist[b];
                if (acc >= (unsigned)TOPK) { bucket = 6144 + b; break; }
            }
        }
        float lo = key_unmap(((unsigned)bucket) << 19) - 2.0f * EPS;
        sh_tk = key_map(lo);
    }
    __syncthreads();

    const unsigned TK = sh_tk;
    u64* erow = emit + (size_t)grow * CAP;
    for (int i = t * 4; i < S_DIM; i += 1024) {
        float4 v = *(const float4*)(prow + i);
        unsigned k[4] = {key_map(v.x), key_map(v.y), key_map(v.z), key_map(v.w)};
#pragma unroll
        for (int j = 0; j < 4; ++j)
            if (k[j] >= TK) {
                int p = atomicAdd(&cnt, 1);
                if (p < CAP) erow[p] = ((u64)k[j] << 32) | (unsigned)(i + j);
            }
    }
    __syncthreads();
    if (t == 0) ccnt[grow] = (cnt < CAP) ? cnt : CAP;
}

__global__ __launch_bounds__(256) void fb_rescore_kernel(
    const float* __restrict__ x, const float* __restrict__ WT,
    const float* __restrict__ benc, const u64* __restrict__ emit,
    const int* __restrict__ ccnt, float* __restrict__ resc,
    const int* __restrict__ flag, int row0)
{
    const int row = row0 + blockIdx.x;
    if (!flag[row]) return;
    const int t = threadIdx.x;
    const int w = t >> 6, l = t & 63;
    const int cnt = ccnt[row];

    __shared__ float xs[K_DIM];
    const float* xr = x + (size_t)row * K_DIM;
    for (int i = t * 4; i < K_DIM; i += 1024)
        *(float4*)&xs[i] = *(const float4*)&xr[i];
    __syncthreads();

    for (int c = w; c < cnt; c += 4) {
        const int s = (int)(emit[(size_t)row * CAP + c] & 0xFFFFFFFFu);
        const float* wc = WT + (size_t)s * K_DIM;
        float acc = 0.f;
#pragma unroll
        for (int j = 0; j < 32; ++j)
            acc = fmaf(xs[l + 64 * j], wc[l + 64 * j], acc);
#pragma unroll
        for (int d = 1; d < 64; d <<= 1) acc += __shfl_xor(acc, d);
        if (l == 0) resc[(size_t)row * CAP + c] = acc + benc[s];
    }
}

__global__ __launch_bounds__(64) void fb_select_kernel(
    const float* __restrict__ resc, const u64* __restrict__ emit,
    const int* __restrict__ ccnt, float* __restrict__ tv,
    int* __restrict__ ti, const int* __restrict__ flag, int row0)
{
    const int row = row0 + blockIdx.x;
    if (!flag[row]) return;
    const int l = threadIdx.x;
    const int cnt = ccnt[row];

    float v[4] = {0.f, 0.f, 0.f, 0.f};
    int   s[4] = {-1, -1, -1, -1};
    u64   p[4] = {0, 0, 0, 0};
#pragma unroll
    for (int j = 0; j < 4; ++j) {
        int c = l + j * 64;
        if (c < cnt) {
            s[j] = (int)(emit[(size_t)row * CAP + c] & 0xFFFFFFFFu);
            v[j] = resc[(size_t)row * CAP + c];
            p[j] = ((u64)key_map(v[j]) << 32) | (unsigned)(~s[j]);
        }
    }

    float* tvr = tv + (size_t)row * TOPK;
    int*   tir = ti + (size_t)row * TOPK;
#pragma unroll 1
    for (int r = 0; r < TOPK; ++r) {
        u64 m = p[0];
        if (p[1] > m) m = p[1];
        if (p[2] > m) m = p[2];
        if (p[3] > m) m = p[3];
#pragma unroll
        for (int d = 1; d < 64; d <<= 1) {
            u64 o = __shfl_xor(m, d);
            if (o > m) m = o;
        }
        if (p[0] == m)      { tvr[r] = v[0]; tir[r] = s[0] < 0 ? 0 : s[0]; p[0] = 0; }
        else if (p[1] == m) { tvr[r] = v[1]; tir[r] = s[1] < 0 ? 0 : s[1]; p[1] = 0; }
        else if (p[2] == m) { tvr[r] = v[2]; tir[r] = s[2] < 0 ? 0 : s[2]; p[2] = 0; }
        else if (p[3] == m) { tvr[r] = v[3]; tir[r] = s[3] < 0 ? 0 : s[3]; p[3] = 0; }
    }
}

// ---------------------------------------------------------------------------
// Decode (verified): out[row] = b_dec + sum relu(tv)*W_dec[ti]
// ---------------------------------------------------------------------------
__global__ __launch_bounds__(256) void decode_kernel(
    const float* __restrict__ tval, const int* __restrict__ tidx,
    const float* __restrict__ Wd, const float* __restrict__ bdec,
    float* __restrict__ out, int row0)
{
    const int row = row0 + blockIdx.x;
    const int t = threadIdx.x;
    __shared__ float sv[TOPK];
    __shared__ int   si[TOPK];
    if (t < TOPK) {
        sv[t] = fmaxf(tval[(size_t)row * TOPK + t], 0.f);
        si[t] = tidx[(size_t)row * TOPK + t];
    }
    __syncthreads();

    const int c0 = t * 4;
    float4 acc0 = *(const float4*)(bdec + c0);
    float4 acc1 = *(const float4*)(bdec + 1024 + c0);
#pragma unroll 4
    for (int i = 0; i < TOPK; ++i) {
        const float z = sv[i];
        if (z > 0.f) {
            const float* wr = Wd + (size_t)si[i] * K_DIM;
            float4 w0 = *(const float4*)(wr + c0);
            float4 w1 = *(const float4*)(wr + 1024 + c0);
            acc0.x = fmaf(z, w0.x, acc0.x); acc0.y = fmaf(z, w0.y, acc0.y);
            acc0.z = fmaf(z, w0.z, acc0.z); acc0.w = fmaf(z, w0.w, acc0.w);
            acc1.x = fmaf(z, w1.x, acc1.x); acc1.y = fmaf(z, w1.y, acc1.y);
            acc1.z = fmaf(z, w1.z, acc1.z); acc1.w = fmaf(z, w1.w, acc1.w);
        }
    }
    float* op = out + (size_t)row * K_DIM;
    *(float4*)(op + c0) = acc0;
    *(float4*)(op + 1024 + c0) = acc1;
}

// ---------------------------------------------------------------------------
extern "C" void kernel_launch(void* const* d_in, const int* in_sizes, int n_in,
                              void* d_out, int out_size, void* d_ws, size_t ws_size,
                              hipStream_t stream)
{
    const float* x     = (const float*)d_in[0];
    const float* W_enc = (const float*)d_in[1];
    const float* W_dec = (const float*)d_in[2];
    const float* b_enc = (const float*)d_in[3];
    const float* b_dec = (const float*)d_in[4];
    float* out = (float*)d_out;

    const int M = in_sizes[0] / K_DIM;   // 4096 batch rows

    // ws layout: tv | ti | emit | ccnt | thrv | flag | resc | Xh | Wh | WT | pre
    char* wsb = (char*)d_ws;
    size_t o = 0;
    float*    tv   = (float*)(wsb + o);    o += (size_t)M * TOPK * 4;
    int*      ti   = (int*)(wsb + o);      o += (size_t)M * TOPK * 4;
    u64*      emit = (u64*)(wsb + o);      o += (size_t)M * CAP * 8;
    int*      ccnt = (int*)(wsb + o);      o += (size_t)M * 4;
    float*    thrv = (float*)(wsb + o);    o += (size_t)M * 4;
    int*      flag = (int*)(wsb + o);      o += (size_t)M * 4;
    float*    resc = (float*)(wsb + o);    o += (size_t)M * CAP * 4;
    u16*      Xh   = (u16*)(wsb + o);      o += (size_t)M * K_DIM * 2;
    u16*      Wh   = (u16*)(wsb + o);      o += (size_t)S_DIM * K_DIM * 2;
    float*    WT   = (float*)(wsb + o);    o += (size_t)S_DIM * K_DIM * 4;
    float*    pre  = (float*)(wsb + o);

    size_t cap = (ws_size > o) ? (ws_size - o) : 0;
    long cap_rows = (long)(cap / ((size_t)S_DIM * 4));
    int chunk = (int)((cap_rows / 256) * 256);
    if (chunk <= 0) chunk = 256;
    if (chunk > M) chunk = M;

    init_kernel<<<(M + 255) / 256, 256, 0, stream>>>(flag, M);
    const int n4 = M * K_DIM / 4;
    conv_x_kernel<<<(n4 + 255) / 256, 256, 0, stream>>>(x, Xh, n4);
    conv_wt_kernel<<<dim3(S_DIM / 64, K_DIM / 64), 256, 0, stream>>>(W_enc, WT, Wh);

    for (int r0 = 0; r0 < M; r0 += chunk) {
        const int rows = (M - r0 < chunk) ? (M - r0) : chunk;
        const int nbm = rows / 256;
        gemm_mfma_kernel<<<nbm * 128, 512, 0, stream>>>(
            Xh + (size_t)r0 * K_DIM, Wh, b_enc, pre);
        screen_kernel<<<rows, 256, 0, stream>>>(pre, emit, ccnt, thrv, flag, r0);
        rescore_kernel<<<rows, 256, 0, stream>>>(x, WT, b_enc, emit, ccnt, thrv, resc, r0);
        select_kernel<<<rows, 64, 0, stream>>>(resc, emit, ccnt, thrv, tv, ti, flag, r0);
        fb_screen_kernel<<<rows, 256, 0, stream>>>(pre, emit, ccnt, flag, r0);
        fb_rescore_kernel<<<rows, 256, 0, stream>>>(x, WT, b_enc, emit, ccnt, resc, flag, r0);
        fb_select_kernel<<<rows, 64, 0, stream>>>(resc, emit, ccnt, tv, ti, flag, r0);
        decode_kernel<<<rows, 256, 0, stream>>>(tv, ti, W_dec, b_dec, out, r0);
    }
}

// Round 9
// 1086.488 us; speedup vs baseline: 1.3989x; 1.1357x over previous
//
#include <hip/hip_runtime.h>
#include <cstdint>
#include <cstddef>

typedef unsigned short u16;
typedef unsigned long long u64;
typedef __attribute__((ext_vector_type(8))) short short8;   // 8 x bf16 fragment
typedef __attribute__((ext_vector_type(4))) float f32x4;    // MFMA accumulator

constexpr int K_DIM = 2048;    // N_POS * D_MODEL (contraction dim for encode)
constexpr int S_DIM = 32768;   // D_SAE
constexpr int TOPK  = 32;
constexpr int CAP   = 256;     // max candidates per row (4 x 64 lanes in select)
#define EPS      0.07f         // bf16-GEMM error (0.06, r3-r8 proven) + bf16-pre rounding (0.008)
#define THR_EMIT 3.7f          // collect floor (needs v32a >= 3.84; 7-sigma safe)
#define HIST_LO  3.5f          // histogram floor, 64 buckets of width 0.04

// ---------------------------------------------------------------------------
__device__ __forceinline__ u16 f2bf(float f) {
    unsigned u = __float_as_uint(f);
    return (u16)((u + 0x7FFFu + ((u >> 16) & 1u)) >> 16);
}
__device__ __forceinline__ float bf2f(u16 h) {
    return __uint_as_float(((unsigned)h) << 16);
}
__device__ __forceinline__ unsigned key_map(float f) {
    unsigned u = __float_as_uint(f);
    return (u & 0x80000000u) ? ~u : (u | 0x80000000u);
}
__device__ __forceinline__ float key_unmap(unsigned k) {
    unsigned u = (k & 0x80000000u) ? (k ^ 0x80000000u) : ~k;
    return __uint_as_float(u);
}

__global__ __launch_bounds__(256) void init_kernel(int* __restrict__ flag, int M)
{
    int i = blockIdx.x * 256 + threadIdx.x;
    if (i < M) flag[i] = 0;
}

// x fp32 -> bf16 (for MFMA screening)
__global__ __launch_bounds__(256) void conv_x_kernel(
    const float* __restrict__ x, u16* __restrict__ hi, int n4)
{
    int i = blockIdx.x * 256 + threadIdx.x;
    if (i >= n4) return;
    float4 v = ((const float4*)x)[i];
    ushort4 h;
    h.x = f2bf(v.x); h.y = f2bf(v.y); h.z = f2bf(v.z); h.w = f2bf(v.w);
    ((ushort4*)hi)[i] = h;
}

// W_enc [K][S] f32 -> WT [S][K] f32 (exact, for rescoring) + Wh [S][K] bf16.
__global__ __launch_bounds__(256) void conv_wt_kernel(
    const float* __restrict__ W, float* __restrict__ WT, u16* __restrict__ Wh)
{
    __shared__ float tile[64][65];
    const int t  = threadIdx.x;
    const int s0 = blockIdx.x * 64;
    const int k0 = blockIdx.y * 64;
#pragma unroll
    for (int i = 0; i < 4; ++i) {
        int kl = (t >> 4) + i * 16;
        int sc = (t & 15) * 4;
        float4 v = *(const float4*)&W[(size_t)(k0 + kl) * S_DIM + s0 + sc];
        tile[kl][sc] = v.x; tile[kl][sc + 1] = v.y;
        tile[kl][sc + 2] = v.z; tile[kl][sc + 3] = v.w;
    }
    __syncthreads();
    const int klc = (t & 7) * 8;
#pragma unroll
    for (int i = 0; i < 2; ++i) {
        int sl = (t >> 3) + i * 32;
        float f[8];
        short8 h8;
#pragma unroll
        for (int j = 0; j < 8; ++j) {
            f[j] = tile[klc + j][sl];
            h8[j] = (short)f2bf(f[j]);
        }
        size_t o = (size_t)(s0 + sl) * K_DIM + k0 + klc;
        *(float4*)&WT[o]     = make_float4(f[0], f[1], f[2], f[3]);
        *(float4*)&WT[o + 4] = make_float4(f[4], f[5], f[6], f[7]);
        *(short8*)&Wh[o] = h8;
    }
}

// ---------------------------------------------------------------------------
// Screening GEMM, 256x256, r8-verified 8-phase K-loop (byte-identical).
// NEW epilogue: bf16 output via LDS transpose -> coalesced short8 stores
// (was 128 scattered 4B stores/thread; WRITE_SIZE 528 -> ~272 MB).
// ---------------------------------------------------------------------------
__device__ __forceinline__ void gl16(const u16* g, u16* s) {
    __builtin_amdgcn_global_load_lds(
        (const __attribute__((address_space(1))) unsigned int*)g,
        (__attribute__((address_space(3))) unsigned int*)s,
        16, 0, 0);
}

#define LGKM0  do { asm volatile("s_waitcnt lgkmcnt(0)" ::: "memory"); \
                    __builtin_amdgcn_sched_barrier(0); } while (0)
#define VMW(n) asm volatile("s_waitcnt vmcnt(" #n ")" ::: "memory")
#define BAR    do { __builtin_amdgcn_s_barrier(); \
                    __builtin_amdgcn_sched_barrier(0); } while (0)

__global__ __launch_bounds__(512, 2) void gemm_mfma_kernel(
    const u16* __restrict__ A, const u16* __restrict__ B,
    const float* __restrict__ bias, u16* __restrict__ Cb)
{
    __shared__ alignas(16) u16 sMem[65536];   // sA[2][16384] | sB[2][16384]
    u16* sA0 = sMem;
    u16* sB0 = sMem + 32768;

    const int t = threadIdx.x;
    const int lane = t & 63;
    const int w = t >> 6;
    const int wm = w >> 2, wn = w & 3;

    const int nwg = gridDim.x;
    const int q = nwg >> 3;
    const int bid = blockIdx.x;
    const int wg = (bid & 7) * q + (bid >> 3);
    const int bm = wg >> 7;
    const int bn = wg & 127;

    const u16* Ab = A + (size_t)bm * 256 * K_DIM;
    const u16* Bb = B + (size_t)bn * 256 * K_DIM;

    const int w2  = w * 2;
    const int lr3 = lane >> 3;
    const int csw = ((lane & 7) ^ lr3) * 8;

    const int rl = lane & 15, kq = lane >> 4;
    const int swz = rl & 7;
    const int ac0 = (kq ^ swz) * 8;
    const int ac1 = ((4 + kq) ^ swz) * 8;
    const int arow = (wm * 16 + rl) * 64;
    const int brow = (wn * 16 + rl) * 64;

    f32x4 acc[8][4];
#pragma unroll
    for (int m = 0; m < 8; ++m)
#pragma unroll
        for (int n = 0; n < 4; ++n) acc[m][n] = (f32x4){0.f, 0.f, 0.f, 0.f};

    auto stA = [&](int half, int j, int kt, int buf) {
        const u16* src = Ab + (size_t)(half * 128 + (w2 + j) * 8 + lr3) * K_DIM
                            + kt * 64 + csw;
        gl16(src, sA0 + buf * 16384 + half * 8192 + (w2 + j) * 512);
    };
    auto stB = [&](int half, int j, int kt, int buf) {
        const u16* src = Bb + (size_t)(half * 128 + (w2 + j) * 8 + lr3) * K_DIM
                            + kt * 64 + csw;
        gl16(src, sB0 + buf * 16384 + half * 8192 + (w2 + j) * 512);
    };

    // Prologue: 7 halves in steady-state FIFO order; drain tile 0 (leave 6).
    stB(0, 0, 0, 0); stB(0, 1, 0, 0);   // Bh0(0)
    stA(0, 0, 0, 0); stA(0, 1, 0, 0);   // Ah0(0)
    stB(1, 0, 0, 0); stB(1, 1, 0, 0);   // Bh1(0)
    stA(1, 0, 0, 0); stA(1, 1, 0, 0);   // Ah1(0)
    stB(0, 0, 1, 1); stB(0, 1, 1, 1);   // Bh0(1)
    stA(0, 0, 1, 1); stA(0, 1, 1, 1);   // Ah0(1)
    stB(1, 0, 1, 1); stB(1, 1, 1, 1);   // Bh1(1)
    VMW(6);
    BAR;

    short8 af[4][2], bf[4][2];

#pragma unroll 1
    for (int it = 0; it < 16; ++it) {
        const bool lastIt = (it == 15);
#pragma unroll
        for (int h = 0; h < 2; ++h) {
            const int b  = h;                  // buffer read this half-iter
            const int tA = 2 * it + 1 + h;     // Ah1 stage tile -> buf b^1
            const int tB = 2 * it + 2 + h;     // Bh0/Ah0/Bh1 stage tile -> buf b

            // ---- ph1: read A m0-3 + B n0-1 (buf b); stage Ah1(tA)
#pragma unroll
            for (int m = 0; m < 4; ++m) {
                af[m][0] = *(const short8*)&sA0[b * 16384 + arow + m * 2048 + ac0];
                af[m][1] = *(const short8*)&sA0[b * 16384 + arow + m * 2048 + ac1];
            }
#pragma unroll
            for (int n = 0; n < 2; ++n) {
                bf[n][0] = *(const short8*)&sB0[b * 16384 + brow + n * 4096 + ac0];
                bf[n][1] = *(const short8*)&sB0[b * 16384 + brow + n * 4096 + ac1];
            }
            if (tA < 32) { stA(1, 0, tA, b ^ 1); stA(1, 1, tA, b ^ 1); }
            __builtin_amdgcn_s_barrier();
            LGKM0;
            __builtin_amdgcn_s_setprio(1);
#pragma unroll
            for (int m = 0; m < 4; ++m)
#pragma unroll
                for (int n = 0; n < 2; ++n)
#pragma unroll
                    for (int kk = 0; kk < 2; ++kk)
                        acc[m][n] = __builtin_amdgcn_mfma_f32_16x16x32_bf16(
                            af[m][kk], bf[n][kk], acc[m][n], 0, 0, 0);
            __builtin_amdgcn_s_setprio(0);
            BAR;

            // ---- ph2: read B n2-3 (buf b); stage Bh0(tB)
#pragma unroll
            for (int n = 2; n < 4; ++n) {
                bf[n][0] = *(const short8*)&sB0[b * 16384 + brow + n * 4096 + ac0];
                bf[n][1] = *(const short8*)&sB0[b * 16384 + brow + n * 4096 + ac1];
            }
            if (tB < 32) { stB(0, 0, tB, b); stB(0, 1, tB, b); }
            __builtin_amdgcn_s_barrier();
            LGKM0;
            __builtin_amdgcn_s_setprio(1);
#pragma unroll
            for (int m = 0; m < 4; ++m)
#pragma unroll
                for (int n = 2; n < 4; ++n)
#pragma unroll
                    for (int kk = 0; kk < 2; ++kk)
                        acc[m][n] = __builtin_amdgcn_mfma_f32_16x16x32_bf16(
                            af[m][kk], bf[n][kk], acc[m][n], 0, 0, 0);
            __builtin_amdgcn_s_setprio(0);
            BAR;

            // ---- ph3: read A m4-7 (buf b); stage Ah0(tB)
#pragma unroll
            for (int m = 0; m < 4; ++m) {
                af[m][0] = *(const short8*)&sA0[b * 16384 + arow + (m + 4) * 2048 + ac0];
                af[m][1] = *(const short8*)&sA0[b * 16384 + arow + (m + 4) * 2048 + ac1];
            }
            if (tB < 32) { stA(0, 0, tB, b); stA(0, 1, tB, b); }
            __builtin_amdgcn_s_barrier();
            LGKM0;
            __builtin_amdgcn_s_setprio(1);
#pragma unroll
            for (int m = 0; m < 4; ++m)
#pragma unroll
                for (int n = 2; n < 4; ++n)
#pragma unroll
                    for (int kk = 0; kk < 2; ++kk)
                        acc[m + 4][n] = __builtin_amdgcn_mfma_f32_16x16x32_bf16(
                            af[m][kk], bf[n][kk], acc[m + 4][n], 0, 0, 0);
            __builtin_amdgcn_s_setprio(0);
            BAR;

            // ---- ph4: no LDS reads; stage Bh1(tB); counted wait
            if (tB < 32) { stB(1, 0, tB, b); stB(1, 1, tB, b); }
            __builtin_amdgcn_s_barrier();
            __builtin_amdgcn_s_setprio(1);
#pragma unroll
            for (int m = 0; m < 4; ++m)
#pragma unroll
                for (int n = 0; n < 2; ++n)
#pragma unroll
                    for (int kk = 0; kk < 2; ++kk)
                        acc[m + 4][n] = __builtin_amdgcn_mfma_f32_16x16x32_bf16(
                            af[m][kk], bf[n][kk], acc[m + 4][n], 0, 0, 0);
            __builtin_amdgcn_s_setprio(0);
            if (lastIt && h == 0) { VMW(0); } else { VMW(6); }
            BAR;
        }
    }

    // ---- epilogue: acc -> bf16 LDS tile [256][256] -> coalesced stores.
    // C/D layout: col = lane&15, row = (lane>>4)*4 + reg.
    {
        const int colL = wn * 16 + rl;        // + n*64
        const int rowL = wm * 16 + kq * 4;    // + m*32 + rr
        float bv[4];
#pragma unroll
        for (int n = 0; n < 4; ++n) bv[n] = bias[bn * 256 + colL + n * 64];
#pragma unroll
        for (int m = 0; m < 8; ++m)
#pragma unroll
            for (int n = 0; n < 4; ++n)
#pragma unroll
                for (int rr = 0; rr < 4; ++rr)
                    sMem[(rowL + m * 32 + rr) * 256 + colL + n * 64] =
                        f2bf(acc[m][n][rr] + bv[n]);
        __syncthreads();

        const int rr2 = t >> 5;               // 0..15
        const int c16 = t & 31;               // 16B chunk in row
        const size_t growB = (size_t)bm * 256;
#pragma unroll
        for (int r = 0; r < 16; ++r) {
            const int lrow = r * 16 + rr2;
            short8 v = *(const short8*)&sMem[lrow * 256 + c16 * 8];
            *(short8*)&Cb[(growB + lrow) * S_DIM + bn * 256 + c16 * 8] = v;
        }
    }
}

// ---------------------------------------------------------------------------
// Screen v4 (structure verified r7/r8, now bf16 input): single pass,
// 64-bucket LDS hist + collect + suffix scan -> refined threshold
// thr = bucket_lo(32nd) - 2*EPS. Guarantee: |bf16approx - exact| <= EPS, so
// {approx >= thr} superset of true top-32. Flag -> exact fallback.
// ---------------------------------------------------------------------------
__global__ __launch_bounds__(256) void screen_kernel(
    const u16* __restrict__ pre, u64* __restrict__ emit,
    int* __restrict__ ccnt, float* __restrict__ thrv,
    int* __restrict__ flag, int row0)
{
    __shared__ unsigned hist[64];
    __shared__ int cnt;

    const int t = threadIdx.x;
    const int row = blockIdx.x;           // chunk-local
    const int grow = row0 + row;
    const u16* prow = pre + (size_t)row * S_DIM;

    if (t < 64) hist[t] = 0;
    if (t == 0) cnt = 0;
    __syncthreads();

    u64* erow = emit + (size_t)grow * CAP;
    for (int i = t * 8; i < S_DIM; i += 2048) {
        short8 v8 = *(const short8*)&prow[i];
#pragma unroll
        for (int j = 0; j < 8; ++j) {
            float v = bf2f((u16)v8[j]);
            if (v >= HIST_LO) {
                int b = (int)((v - HIST_LO) * 25.0f);
                if (b > 63) b = 63;
                atomicAdd(&hist[b], 1u);
                if (v >= THR_EMIT) {
                    int p = atomicAdd(&cnt, 1);
                    if (p < CAP)
                        erow[p] = ((u64)key_map(v) << 32) | (unsigned)(i + j);
                }
            }
        }
    }
    __syncthreads();

    if (t == 0) {
        unsigned acc = 0;
        int b = -1;
        for (int j = 63; j >= 0; --j) {
            acc += hist[j];
            if (acc >= (unsigned)TOPK) { b = j; break; }
        }
        float thr = HIST_LO + 0.04f * b - 2.0f * EPS - 1e-4f;
        if (b < 0 || cnt > CAP || thr < THR_EMIT) {
            flag[grow] = 1;
            thr = THR_EMIT;
        }
        thrv[grow] = thr;
        ccnt[grow] = (cnt < CAP) ? cnt : CAP;
    }
}

// ---------------------------------------------------------------------------
// Rescore: exact fp32 dot for candidates passing the refined threshold.
// ---------------------------------------------------------------------------
__global__ __launch_bounds__(256) void rescore_kernel(
    const float* __restrict__ x, const float* __restrict__ WT,
    const float* __restrict__ benc, const u64* __restrict__ emit,
    const int* __restrict__ ccnt, const float* __restrict__ thrv,
    float* __restrict__ resc, int row0)
{
    const int row = row0 + blockIdx.x;
    const int t = threadIdx.x;
    const int w = t >> 6, l = t & 63;
    const int cnt = ccnt[row];
    const float thr = thrv[row];

    __shared__ float xs[K_DIM];
    const float* xr = x + (size_t)row * K_DIM;
    for (int i = t * 4; i < K_DIM; i += 1024)
        *(float4*)&xs[i] = *(const float4*)&xr[i];
    __syncthreads();

    for (int c = w; c < cnt; c += 4) {
        const u64 pk = emit[(size_t)row * CAP + c];
        const float approx = key_unmap((unsigned)(pk >> 32));
        if (approx < thr) {
            if (l == 0) resc[(size_t)row * CAP + c] = -3e38f;
            continue;
        }
        const int s = (int)(pk & 0xFFFFFFFFu);
        const float* wc = WT + (size_t)s * K_DIM;
        float acc = 0.f;
#pragma unroll
        for (int j = 0; j < 32; ++j)
            acc = fmaf(xs[l + 64 * j], wc[l + 64 * j], acc);
#pragma unroll
        for (int d = 1; d < 64; d <<= 1) acc += __shfl_xor(acc, d);
        if (l == 0) resc[(size_t)row * CAP + c] = acc + benc[s];
    }
}

// ---------------------------------------------------------------------------
// Select: exact top-32 (value desc, index asc) + exactness validation:
//   v32_rescored >= thr + EPS proves no below-threshold item can be top-32.
// ---------------------------------------------------------------------------
__global__ __launch_bounds__(64) void select_kernel(
    const float* __restrict__ resc, const u64* __restrict__ emit,
    const int* __restrict__ ccnt, const float* __restrict__ thrv,
    float* __restrict__ tv, int* __restrict__ ti, int* __restrict__ flag,
    int row0)
{
    const int row = row0 + blockIdx.x;
    const int l = threadIdx.x;
    const int cnt = ccnt[row];

    float v[4] = {0.f, 0.f, 0.f, 0.f};
    int   s[4] = {-1, -1, -1, -1};
    u64   p[4] = {0, 0, 0, 0};
#pragma unroll
    for (int j = 0; j < 4; ++j) {
        int c = l + j * 64;
        if (c < cnt) {
            s[j] = (int)(emit[(size_t)row * CAP + c] & 0xFFFFFFFFu);
            v[j] = resc[(size_t)row * CAP + c];
            p[j] = ((u64)key_map(v[j]) << 32) | (unsigned)(~s[j]);
        }
    }

    float* tvr = tv + (size_t)row * TOPK;
    int*   tir = ti + (size_t)row * TOPK;
    float v32f = -3e38f;
#pragma unroll 1
    for (int r = 0; r < TOPK; ++r) {
        u64 m = p[0];
        if (p[1] > m) m = p[1];
        if (p[2] > m) m = p[2];
        if (p[3] > m) m = p[3];
#pragma unroll
        for (int d = 1; d < 64; d <<= 1) {
            u64 o = __shfl_xor(m, d);
            if (o > m) m = o;
        }
        if (r == TOPK - 1) v32f = key_unmap((unsigned)(m >> 32));
        if (p[0] == m)      { tvr[r] = v[0]; tir[r] = s[0] < 0 ? 0 : s[0]; p[0] = 0; }
        else if (p[1] == m) { tvr[r] = v[1]; tir[r] = s[1] < 0 ? 0 : s[1]; p[1] = 0; }
        else if (p[2] == m) { tvr[r] = v[2]; tir[r] = s[2] < 0 ? 0 : s[2]; p[2] = 0; }
        else if (p[3] == m) { tvr[r] = v[3]; tir[r] = s[3] < 0 ? 0 : s[3]; p[3] = 0; }
    }
    if (l == 0) {
        if (v32f < thrv[row] + EPS) flag[row] = 1;
    }
}

// ---------------------------------------------------------------------------
// Fallback (flag-guarded, normally 0 active rows): exact fine-histogram
// screen over the bf16 pre row, then rescore + select.
// ---------------------------------------------------------------------------
__global__ __launch_bounds__(256) void fb_screen_kernel(
    const u16* __restrict__ pre, u64* __restrict__ emit,
    int* __restrict__ ccnt, const int* __restrict__ flag, int row0)
{
    const int grow = row0 + blockIdx.x;
    if (!flag[grow]) return;

    __shared__ unsigned hist[2048];
    __shared__ unsigned partial[256];
    __shared__ unsigned sh_tk;
    __shared__ int cnt;

    const int t = threadIdx.x;
    const u16* prow = pre + (size_t)blockIdx.x * S_DIM;

    for (int i = t; i < 2048; i += 256) hist[i] = 0;
    if (t == 0) cnt = 0;
    __syncthreads();

    for (int i = t * 8; i < S_DIM; i += 2048) {
        short8 v8 = *(const short8*)&prow[i];
#pragma unroll
        for (int j = 0; j < 8; ++j) {
            unsigned k = key_map(bf2f((u16)v8[j]));
            if (k >= 0xC0000000u) atomicAdd(&hist[(k >> 19) - 6144], 1u);
        }
    }
    __syncthreads();

    unsigned ps = 0;
#pragma unroll
    for (int j = 0; j < 8; ++j) ps += hist[t * 8 + j];
    partial[t] = ps;
    __syncthreads();

    if (t == 0) {
        unsigned acc = 0;
        int seg = -1;
        for (int s = 255; s >= 0; --s) {
            if (acc + partial[s] >= (unsigned)TOPK) { seg = s; break; }
            acc += partial[s];
        }
        int bucket = 6144;
        if (seg >= 0) {
            for (int b = seg * 8 + 7; b >= seg * 8; --b) {
                acc += hist[b];
                if (acc >= (unsigned)TOPK) { bucket = 6144 + b; break; }
            }
        }
        float lo = key_unmap(((unsigned)bucket) << 19) - 2.0f * EPS;
        sh_tk = key_map(lo);
    }
    __syncthreads();

    const unsigned TK = sh_tk;
    u64* erow = emit + (size_t)grow * CAP;
    for (int i = t * 8; i < S_DIM; i += 2048) {
        short8 v8 = *(const short8*)&prow[i];
#pragma unroll
        for (int j = 0; j < 8; ++j) {
            unsigned k = key_map(bf2f((u16)v8[j]));
            if (k >= TK) {
                int p = atomicAdd(&cnt, 1);
                if (p < CAP) erow[p] = ((u64)k << 32) | (unsigned)(i + j);
            }
        }
    }
    __syncthreads();
    if (t == 0) ccnt[grow] = (cnt < CAP) ? cnt : CAP;
}

__global__ __launch_bounds__(256) void fb_rescore_kernel(
    const float* __restrict__ x, const float* __restrict__ WT,
    const float* __restrict__ benc, const u64* __restrict__ emit,
    const int* __restrict__ ccnt, float* __restrict__ resc,
    const int* __restrict__ flag, int row0)
{
    const int row = row0 + blockIdx.x;
    if (!flag[row]) return;
    const int t = threadIdx.x;
    const int w = t >> 6, l = t & 63;
    const int cnt = ccnt[row];

    __shared__ float xs[K_DIM];
    const float* xr = x + (size_t)row * K_DIM;
    for (int i = t * 4; i < K_DIM; i += 1024)
        *(float4*)&xs[i] = *(const float4*)&xr[i];
    __syncthreads();

    for (int c = w; c < cnt; c += 4) {
        const int s = (int)(emit[(size_t)row * CAP + c] & 0xFFFFFFFFu);
        const float* wc = WT + (size_t)s * K_DIM;
        float acc = 0.f;
#pragma unroll
        for (int j = 0; j < 32; ++j)
            acc = fmaf(xs[l + 64 * j], wc[l + 64 * j], acc);
#pragma unroll
        for (int d = 1; d < 64; d <<= 1) acc += __shfl_xor(acc, d);
        if (l == 0) resc[(size_t)row * CAP + c] = acc + benc[s];
    }
}

__global__ __launch_bounds__(64) void fb_select_kernel(
    const float* __restrict__ resc, const u64* __restrict__ emit,
    const int* __restrict__ ccnt, float* __restrict__ tv,
    int* __restrict__ ti, const int* __restrict__ flag, int row0)
{
    const int row = row0 + blockIdx.x;
    if (!flag[row]) return;
    const int l = threadIdx.x;
    const int cnt = ccnt[row];

    float v[4] = {0.f, 0.f, 0.f, 0.f};
    int   s[4] = {-1, -1, -1, -1};
    u64   p[4] = {0, 0, 0, 0};
#pragma unroll
    for (int j = 0; j < 4; ++j) {
        int c = l + j * 64;
        if (c < cnt) {
            s[j] = (int)(emit[(size_t)row * CAP + c] & 0xFFFFFFFFu);
            v[j] = resc[(size_t)row * CAP + c];
            p[j] = ((u64)key_map(v[j]) << 32) | (unsigned)(~s[j]);
        }
    }

    float* tvr = tv + (size_t)row * TOPK;
    int*   tir = ti + (size_t)row * TOPK;
#pragma unroll 1
    for (int r = 0; r < TOPK; ++r) {
        u64 m = p[0];
        if (p[1] > m) m = p[1];
        if (p[2] > m) m = p[2];
        if (p[3] > m) m = p[3];
#pragma unroll
        for (int d = 1; d < 64; d <<= 1) {
            u64 o = __shfl_xor(m, d);
            if (o > m) m = o;
        }
        if (p[0] == m)      { tvr[r] = v[0]; tir[r] = s[0] < 0 ? 0 : s[0]; p[0] = 0; }
        else if (p[1] == m) { tvr[r] = v[1]; tir[r] = s[1] < 0 ? 0 : s[1]; p[1] = 0; }
        else if (p[2] == m) { tvr[r] = v[2]; tir[r] = s[2] < 0 ? 0 : s[2]; p[2] = 0; }
        else if (p[3] == m) { tvr[r] = v[3]; tir[r] = s[3] < 0 ? 0 : s[3]; p[3] = 0; }
    }
}

// ---------------------------------------------------------------------------
// Decode (verified): out[row] = b_dec + sum relu(tv)*W_dec[ti]
// ---------------------------------------------------------------------------
__global__ __launch_bounds__(256) void decode_kernel(
    const float* __restrict__ tval, const int* __restrict__ tidx,
    const float* __restrict__ Wd, const float* __restrict__ bdec,
    float* __restrict__ out, int row0)
{
    const int row = row0 + blockIdx.x;
    const int t = threadIdx.x;
    __shared__ float sv[TOPK];
    __shared__ int   si[TOPK];
    if (t < TOPK) {
        sv[t] = fmaxf(tval[(size_t)row * TOPK + t], 0.f);
        si[t] = tidx[(size_t)row * TOPK + t];
    }
    __syncthreads();

    const int c0 = t * 4;
    float4 acc0 = *(const float4*)(bdec + c0);
    float4 acc1 = *(const float4*)(bdec + 1024 + c0);
#pragma unroll 4
    for (int i = 0; i < TOPK; ++i) {
        const float z = sv[i];
        if (z > 0.f) {
            const float* wr = Wd + (size_t)si[i] * K_DIM;
            float4 w0 = *(const float4*)(wr + c0);
            float4 w1 = *(const float4*)(wr + 1024 + c0);
            acc0.x = fmaf(z, w0.x, acc0.x); acc0.y = fmaf(z, w0.y, acc0.y);
            acc0.z = fmaf(z, w0.z, acc0.z); acc0.w = fmaf(z, w0.w, acc0.w);
            acc1.x = fmaf(z, w1.x, acc1.x); acc1.y = fmaf(z, w1.y, acc1.y);
            acc1.z = fmaf(z, w1.z, acc1.z); acc1.w = fmaf(z, w1.w, acc1.w);
        }
    }
    float* op = out + (size_t)row * K_DIM;
    *(float4*)(op + c0) = acc0;
    *(float4*)(op + 1024 + c0) = acc1;
}

// ---------------------------------------------------------------------------
extern "C" void kernel_launch(void* const* d_in, const int* in_sizes, int n_in,
                              void* d_out, int out_size, void* d_ws, size_t ws_size,
                              hipStream_t stream)
{
    const float* x     = (const float*)d_in[0];
    const float* W_enc = (const float*)d_in[1];
    const float* W_dec = (const float*)d_in[2];
    const float* b_enc = (const float*)d_in[3];
    const float* b_dec = (const float*)d_in[4];
    float* out = (float*)d_out;

    const int M = in_sizes[0] / K_DIM;   // 4096 batch rows

    // ws layout: tv | ti | emit | ccnt | thrv | flag | resc | Xh | Wh | WT | pre(bf16)
    char* wsb = (char*)d_ws;
    size_t o = 0;
    float*    tv   = (float*)(wsb + o);    o += (size_t)M * TOPK * 4;
    int*      ti   = (int*)(wsb + o);      o += (size_t)M * TOPK * 4;
    u64*      emit = (u64*)(wsb + o);      o += (size_t)M * CAP * 8;
    int*      ccnt = (int*)(wsb + o);      o += (size_t)M * 4;
    float*    thrv = (float*)(wsb + o);    o += (size_t)M * 4;
    int*      flag = (int*)(wsb + o);      o += (size_t)M * 4;
    float*    resc = (float*)(wsb + o);    o += (size_t)M * CAP * 4;
    u16*      Xh   = (u16*)(wsb + o);      o += (size_t)M * K_DIM * 2;
    u16*      Wh   = (u16*)(wsb + o);      o += (size_t)S_DIM * K_DIM * 2;
    float*    WT   = (float*)(wsb + o);    o += (size_t)S_DIM * K_DIM * 4;
    u16*      pre  = (u16*)(wsb + o);

    size_t cap = (ws_size > o) ? (ws_size - o) : 0;
    long cap_rows = (long)(cap / ((size_t)S_DIM * 2));
    int chunk = (int)((cap_rows / 256) * 256);
    if (chunk <= 0) chunk = 256;
    if (chunk > M) chunk = M;

    init_kernel<<<(M + 255) / 256, 256, 0, stream>>>(flag, M);
    const int n4 = M * K_DIM / 4;
    conv_x_kernel<<<(n4 + 255) / 256, 256, 0, stream>>>(x, Xh, n4);
    conv_wt_kernel<<<dim3(S_DIM / 64, K_DIM / 64), 256, 0, stream>>>(W_enc, WT, Wh);

    for (int r0 = 0; r0 < M; r0 += chunk) {
        const int rows = (M - r0 < chunk) ? (M - r0) : chunk;
        const int nbm = rows / 256;
        gemm_mfma_kernel<<<nbm * 128, 512, 0, stream>>>(
            Xh + (size_t)r0 * K_DIM, Wh, b_enc, pre);
        screen_kernel<<<rows, 256, 0, stream>>>(pre, emit, ccnt, thrv, flag, r0);
        rescore_kernel<<<rows, 256, 0, stream>>>(x, WT, b_enc, emit, ccnt, thrv, resc, r0);
        select_kernel<<<rows, 64, 0, stream>>>(resc, emit, ccnt, thrv, tv, ti, flag, r0);
        fb_screen_kernel<<<rows, 256, 0, stream>>>(pre, emit, ccnt, flag, r0);
        fb_rescore_kernel<<<rows, 256, 0, stream>>>(x, WT, b_enc, emit, ccnt, resc, flag, r0);
        fb_select_kernel<<<rows, 64, 0, stream>>>(resc, emit, ccnt, tv, ti, flag, r0);
        decode_kernel<<<rows, 256, 0, stream>>>(tv, ti, W_dec, b_dec, out, r0);
    }
}

// Round 10
// 1084.035 us; speedup vs baseline: 1.4020x; 1.0023x over previous
//
#include <hip/hip_runtime.h>
#include <cstdint>
#include <cstddef>

typedef unsigned short u16;
typedef unsigned long long u64;
typedef __attribute__((ext_vector_type(8))) short short8;   // 8 x bf16 fragment
typedef __attribute__((ext_vector_type(4))) float f32x4;    // MFMA accumulator

constexpr int K_DIM = 2048;    // N_POS * D_MODEL (contraction dim for encode)
constexpr int S_DIM = 32768;   // D_SAE
constexpr int TOPK  = 32;
constexpr int CAP   = 256;     // max candidates per row (4 x 64 lanes in select)
#define EPS      0.07f         // bf16-GEMM error (0.06, r3-r8 proven) + bf16-pre rounding (0.008)
#define THR_EMIT 3.7f          // collect floor (needs v32a >= 3.84; 7-sigma safe)
#define HIST_LO  3.5f          // histogram floor, 64 buckets of width 0.04

// ---------------------------------------------------------------------------
__device__ __forceinline__ u16 f2bf(float f) {
    unsigned u = __float_as_uint(f);
    return (u16)((u + 0x7FFFu + ((u >> 16) & 1u)) >> 16);
}
__device__ __forceinline__ float bf2f(u16 h) {
    return __uint_as_float(((unsigned)h) << 16);
}
__device__ __forceinline__ unsigned key_map(float f) {
    unsigned u = __float_as_uint(f);
    return (u & 0x80000000u) ? ~u : (u | 0x80000000u);
}
__device__ __forceinline__ float key_unmap(unsigned k) {
    unsigned u = (k & 0x80000000u) ? (k ^ 0x80000000u) : ~k;
    return __uint_as_float(u);
}

__global__ __launch_bounds__(256) void init_kernel(int* __restrict__ flag, int M)
{
    int i = blockIdx.x * 256 + threadIdx.x;
    if (i < M) flag[i] = 0;
}

// x fp32 -> bf16 (for MFMA screening)
__global__ __launch_bounds__(256) void conv_x_kernel(
    const float* __restrict__ x, u16* __restrict__ hi, int n4)
{
    int i = blockIdx.x * 256 + threadIdx.x;
    if (i >= n4) return;
    float4 v = ((const float4*)x)[i];
    ushort4 h;
    h.x = f2bf(v.x); h.y = f2bf(v.y); h.z = f2bf(v.z); h.w = f2bf(v.w);
    ((ushort4*)hi)[i] = h;
}

// W_enc [K][S] f32 -> WT [S][K] f32 (exact, for rescoring) + Wh [S][K] bf16.
__global__ __launch_bounds__(256) void conv_wt_kernel(
    const float* __restrict__ W, float* __restrict__ WT, u16* __restrict__ Wh)
{
    __shared__ float tile[64][65];
    const int t  = threadIdx.x;
    const int s0 = blockIdx.x * 64;
    const int k0 = blockIdx.y * 64;
#pragma unroll
    for (int i = 0; i < 4; ++i) {
        int kl = (t >> 4) + i * 16;
        int sc = (t & 15) * 4;
        float4 v = *(const float4*)&W[(size_t)(k0 + kl) * S_DIM + s0 + sc];
        tile[kl][sc] = v.x; tile[kl][sc + 1] = v.y;
        tile[kl][sc + 2] = v.z; tile[kl][sc + 3] = v.w;
    }
    __syncthreads();
    const int klc = (t & 7) * 8;
#pragma unroll
    for (int i = 0; i < 2; ++i) {
        int sl = (t >> 3) + i * 32;
        float f[8];
        short8 h8;
#pragma unroll
        for (int j = 0; j < 8; ++j) {
            f[j] = tile[klc + j][sl];
            h8[j] = (short)f2bf(f[j]);
        }
        size_t o = (size_t)(s0 + sl) * K_DIM + k0 + klc;
        *(float4*)&WT[o]     = make_float4(f[0], f[1], f[2], f[3]);
        *(float4*)&WT[o + 4] = make_float4(f[4], f[5], f[6], f[7]);
        *(short8*)&Wh[o] = h8;
    }
}

// ---------------------------------------------------------------------------
// Screening GEMM, 256x256, r8/r9 staging schedule with BALANCED LDS phases:
// ds_reads per phase 8/4/8/4 (was 12/4/8/0) — B n0-1 fragments of tile kt+1
// are read in ph4 of tile kt, AFTER the VMW(6) (which drains all of tile
// kt+1's staged halves: FIFO queue at that point has 7 units, drains 4 =
// Bh0/Ah0/Bh1/Ah1 of kt+1). Buffers, staging order, vmcnt math, swizzle,
// epilogue = r9 verified bytes.
// ---------------------------------------------------------------------------
__device__ __forceinline__ void gl16(const u16* g, u16* s) {
    __builtin_amdgcn_global_load_lds(
        (const __attribute__((address_space(1))) unsigned int*)g,
        (__attribute__((address_space(3))) unsigned int*)s,
        16, 0, 0);
}

#define LGKM0  do { asm volatile("s_waitcnt lgkmcnt(0)" ::: "memory"); \
                    __builtin_amdgcn_sched_barrier(0); } while (0)
#define VMW(n) asm volatile("s_waitcnt vmcnt(" #n ")" ::: "memory")
#define BAR    do { __builtin_amdgcn_s_barrier(); \
                    __builtin_amdgcn_sched_barrier(0); } while (0)

__global__ __launch_bounds__(512, 2) void gemm_mfma_kernel(
    const u16* __restrict__ A, const u16* __restrict__ B,
    const float* __restrict__ bias, u16* __restrict__ Cb)
{
    __shared__ alignas(16) u16 sMem[65536];   // sA[2][16384] | sB[2][16384]
    u16* sA0 = sMem;
    u16* sB0 = sMem + 32768;

    const int t = threadIdx.x;
    const int lane = t & 63;
    const int w = t >> 6;
    const int wm = w >> 2, wn = w & 3;

    const int nwg = gridDim.x;
    const int q = nwg >> 3;
    const int bid = blockIdx.x;
    const int wg = (bid & 7) * q + (bid >> 3);
    const int bm = wg >> 7;
    const int bn = wg & 127;

    const u16* Ab = A + (size_t)bm * 256 * K_DIM;
    const u16* Bb = B + (size_t)bn * 256 * K_DIM;

    const int w2  = w * 2;
    const int lr3 = lane >> 3;
    const int csw = ((lane & 7) ^ lr3) * 8;

    const int rl = lane & 15, kq = lane >> 4;
    const int swz = rl & 7;
    const int ac0 = (kq ^ swz) * 8;
    const int ac1 = ((4 + kq) ^ swz) * 8;
    const int arow = (wm * 16 + rl) * 64;
    const int brow = (wn * 16 + rl) * 64;

    f32x4 acc[8][4];
#pragma unroll
    for (int m = 0; m < 8; ++m)
#pragma unroll
        for (int n = 0; n < 4; ++n) acc[m][n] = (f32x4){0.f, 0.f, 0.f, 0.f};

    auto stA = [&](int half, int j, int kt, int buf) {
        const u16* src = Ab + (size_t)(half * 128 + (w2 + j) * 8 + lr3) * K_DIM
                            + kt * 64 + csw;
        gl16(src, sA0 + buf * 16384 + half * 8192 + (w2 + j) * 512);
    };
    auto stB = [&](int half, int j, int kt, int buf) {
        const u16* src = Bb + (size_t)(half * 128 + (w2 + j) * 8 + lr3) * K_DIM
                            + kt * 64 + csw;
        gl16(src, sB0 + buf * 16384 + half * 8192 + (w2 + j) * 512);
    };

    // Prologue: 7 halves in steady-state FIFO order; drain tile 0 (leave 6).
    stB(0, 0, 0, 0); stB(0, 1, 0, 0);   // Bh0(0)
    stA(0, 0, 0, 0); stA(0, 1, 0, 0);   // Ah0(0)
    stB(1, 0, 0, 0); stB(1, 1, 0, 0);   // Bh1(0)
    stA(1, 0, 0, 0); stA(1, 1, 0, 0);   // Ah1(0)
    stB(0, 0, 1, 1); stB(0, 1, 1, 1);   // Bh0(1)
    stA(0, 0, 1, 1); stA(0, 1, 1, 1);   // Ah0(1)
    stB(1, 0, 1, 1); stB(1, 1, 1, 1);   // Bh1(1)
    VMW(6);
    BAR;

    short8 af[4][2], bf[4][2];

    // preload tile-0 B n0-1 fragments (buf 0)
#pragma unroll
    for (int n = 0; n < 2; ++n) {
        bf[n][0] = *(const short8*)&sB0[brow + n * 4096 + ac0];
        bf[n][1] = *(const short8*)&sB0[brow + n * 4096 + ac1];
    }

#pragma unroll 1
    for (int it = 0; it < 16; ++it) {
        const bool lastIt = (it == 15);
#pragma unroll
        for (int h = 0; h < 2; ++h) {
            const int b  = h;                  // buffer read this half-iter
            const int tA = 2 * it + 1 + h;     // Ah1 stage tile -> buf b^1
            const int tB = 2 * it + 2 + h;     // Bh0/Ah0/Bh1 stage tile -> buf b

            // ---- ph1: read A m0-3 (8 reads; bf[0-1] already in regs);
            //           stage Ah1(tA)
#pragma unroll
            for (int m = 0; m < 4; ++m) {
                af[m][0] = *(const short8*)&sA0[b * 16384 + arow + m * 2048 + ac0];
                af[m][1] = *(const short8*)&sA0[b * 16384 + arow + m * 2048 + ac1];
            }
            if (tA < 32) { stA(1, 0, tA, b ^ 1); stA(1, 1, tA, b ^ 1); }
            __builtin_amdgcn_s_barrier();
            LGKM0;
            __builtin_amdgcn_s_setprio(1);
#pragma unroll
            for (int m = 0; m < 4; ++m)
#pragma unroll
                for (int n = 0; n < 2; ++n)
#pragma unroll
                    for (int kk = 0; kk < 2; ++kk)
                        acc[m][n] = __builtin_amdgcn_mfma_f32_16x16x32_bf16(
                            af[m][kk], bf[n][kk], acc[m][n], 0, 0, 0);
            __builtin_amdgcn_s_setprio(0);
            BAR;

            // ---- ph2: read B n2-3 (4 reads); stage Bh0(tB)
#pragma unroll
            for (int n = 2; n < 4; ++n) {
                bf[n][0] = *(const short8*)&sB0[b * 16384 + brow + n * 4096 + ac0];
                bf[n][1] = *(const short8*)&sB0[b * 16384 + brow + n * 4096 + ac1];
            }
            if (tB < 32) { stB(0, 0, tB, b); stB(0, 1, tB, b); }
            __builtin_amdgcn_s_barrier();
            LGKM0;
            __builtin_amdgcn_s_setprio(1);
#pragma unroll
            for (int m = 0; m < 4; ++m)
#pragma unroll
                for (int n = 2; n < 4; ++n)
#pragma unroll
                    for (int kk = 0; kk < 2; ++kk)
                        acc[m][n] = __builtin_amdgcn_mfma_f32_16x16x32_bf16(
                            af[m][kk], bf[n][kk], acc[m][n], 0, 0, 0);
            __builtin_amdgcn_s_setprio(0);
            BAR;

            // ---- ph3: read A m4-7 (8 reads); stage Ah0(tB)
#pragma unroll
            for (int m = 0; m < 4; ++m) {
                af[m][0] = *(const short8*)&sA0[b * 16384 + arow + (m + 4) * 2048 + ac0];
                af[m][1] = *(const short8*)&sA0[b * 16384 + arow + (m + 4) * 2048 + ac1];
            }
            if (tB < 32) { stA(0, 0, tB, b); stA(0, 1, tB, b); }
            __builtin_amdgcn_s_barrier();
            LGKM0;
            __builtin_amdgcn_s_setprio(1);
#pragma unroll
            for (int m = 0; m < 4; ++m)
#pragma unroll
                for (int n = 2; n < 4; ++n)
#pragma unroll
                    for (int kk = 0; kk < 2; ++kk)
                        acc[m + 4][n] = __builtin_amdgcn_mfma_f32_16x16x32_bf16(
                            af[m][kk], bf[n][kk], acc[m + 4][n], 0, 0, 0);
            __builtin_amdgcn_s_setprio(0);
            BAR;

            // ---- ph4: stage Bh1(tB); MFMA m4-7 x n0-1; counted wait;
            //           then read NEXT tile's B n0-1 (4 reads, post-VMW)
            if (tB < 32) { stB(1, 0, tB, b); stB(1, 1, tB, b); }
            __builtin_amdgcn_s_barrier();
            __builtin_amdgcn_s_setprio(1);
#pragma unroll
            for (int m = 0; m < 4; ++m)
#pragma unroll
                for (int n = 0; n < 2; ++n)
#pragma unroll
                    for (int kk = 0; kk < 2; ++kk)
                        acc[m + 4][n] = __builtin_amdgcn_mfma_f32_16x16x32_bf16(
                            af[m][kk], bf[n][kk], acc[m + 4][n], 0, 0, 0);
            __builtin_amdgcn_s_setprio(0);
            if (lastIt && h == 0) { VMW(0); } else { VMW(6); }
            if (!(lastIt && h == 1)) {
#pragma unroll
                for (int n = 0; n < 2; ++n) {
                    bf[n][0] = *(const short8*)&sB0[(b ^ 1) * 16384 + brow + n * 4096 + ac0];
                    bf[n][1] = *(const short8*)&sB0[(b ^ 1) * 16384 + brow + n * 4096 + ac1];
                }
            }
            BAR;
        }
    }

    // ---- epilogue: acc -> bf16 LDS tile [256][256] -> coalesced stores.
    // C/D layout: col = lane&15, row = (lane>>4)*4 + reg.
    {
        const int colL = wn * 16 + rl;        // + n*64
        const int rowL = wm * 16 + kq * 4;    // + m*32 + rr
        float bv[4];
#pragma unroll
        for (int n = 0; n < 4; ++n) bv[n] = bias[bn * 256 + colL + n * 64];
#pragma unroll
        for (int m = 0; m < 8; ++m)
#pragma unroll
            for (int n = 0; n < 4; ++n)
#pragma unroll
                for (int rr = 0; rr < 4; ++rr)
                    sMem[(rowL + m * 32 + rr) * 256 + colL + n * 64] =
                        f2bf(acc[m][n][rr] + bv[n]);
        __syncthreads();

        const int rr2 = t >> 5;               // 0..15
        const int c16 = t & 31;               // 16B chunk in row
        const size_t growB = (size_t)bm * 256;
#pragma unroll
        for (int r = 0; r < 16; ++r) {
            const int lrow = r * 16 + rr2;
            short8 v = *(const short8*)&sMem[lrow * 256 + c16 * 8];
            *(short8*)&Cb[(growB + lrow) * S_DIM + bn * 256 + c16 * 8] = v;
        }
    }
}

// ---------------------------------------------------------------------------
// Screen v4 (verified r9): single pass over bf16 pre, 64-bucket LDS hist +
// collect + suffix scan -> refined threshold thr = bucket_lo(32nd) - 2*EPS.
// ---------------------------------------------------------------------------
__global__ __launch_bounds__(256) void screen_kernel(
    const u16* __restrict__ pre, u64* __restrict__ emit,
    int* __restrict__ ccnt, float* __restrict__ thrv,
    int* __restrict__ flag, int row0)
{
    __shared__ unsigned hist[64];
    __shared__ int cnt;

    const int t = threadIdx.x;
    const int row = blockIdx.x;           // chunk-local
    const int grow = row0 + row;
    const u16* prow = pre + (size_t)row * S_DIM;

    if (t < 64) hist[t] = 0;
    if (t == 0) cnt = 0;
    __syncthreads();

    u64* erow = emit + (size_t)grow * CAP;
    for (int i = t * 8; i < S_DIM; i += 2048) {
        short8 v8 = *(const short8*)&prow[i];
#pragma unroll
        for (int j = 0; j < 8; ++j) {
            float v = bf2f((u16)v8[j]);
            if (v >= HIST_LO) {
                int b = (int)((v - HIST_LO) * 25.0f);
                if (b > 63) b = 63;
                atomicAdd(&hist[b], 1u);
                if (v >= THR_EMIT) {
                    int p = atomicAdd(&cnt, 1);
                    if (p < CAP)
                        erow[p] = ((u64)key_map(v) << 32) | (unsigned)(i + j);
                }
            }
        }
    }
    __syncthreads();

    if (t == 0) {
        unsigned acc = 0;
        int b = -1;
        for (int j = 63; j >= 0; --j) {
            acc += hist[j];
            if (acc >= (unsigned)TOPK) { b = j; break; }
        }
        float thr = HIST_LO + 0.04f * b - 2.0f * EPS - 1e-4f;
        if (b < 0 || cnt > CAP || thr < THR_EMIT) {
            flag[grow] = 1;
            thr = THR_EMIT;
        }
        thrv[grow] = thr;
        ccnt[grow] = (cnt < CAP) ? cnt : CAP;
    }
}

// ---------------------------------------------------------------------------
// Rescore: exact fp32 dot for candidates passing the refined threshold.
// ---------------------------------------------------------------------------
__global__ __launch_bounds__(256) void rescore_kernel(
    const float* __restrict__ x, const float* __restrict__ WT,
    const float* __restrict__ benc, const u64* __restrict__ emit,
    const int* __restrict__ ccnt, const float* __restrict__ thrv,
    float* __restrict__ resc, int row0)
{
    const int row = row0 + blockIdx.x;
    const int t = threadIdx.x;
    const int w = t >> 6, l = t & 63;
    const int cnt = ccnt[row];
    const float thr = thrv[row];

    __shared__ float xs[K_DIM];
    const float* xr = x + (size_t)row * K_DIM;
    for (int i = t * 4; i < K_DIM; i += 1024)
        *(float4*)&xs[i] = *(const float4*)&xr[i];
    __syncthreads();

    for (int c = w; c < cnt; c += 4) {
        const u64 pk = emit[(size_t)row * CAP + c];
        const float approx = key_unmap((unsigned)(pk >> 32));
        if (approx < thr) {
            if (l == 0) resc[(size_t)row * CAP + c] = -3e38f;
            continue;
        }
        const int s = (int)(pk & 0xFFFFFFFFu);
        const float* wc = WT + (size_t)s * K_DIM;
        float acc = 0.f;
#pragma unroll
        for (int j = 0; j < 32; ++j)
            acc = fmaf(xs[l + 64 * j], wc[l + 64 * j], acc);
#pragma unroll
        for (int d = 1; d < 64; d <<= 1) acc += __shfl_xor(acc, d);
        if (l == 0) resc[(size_t)row * CAP + c] = acc + benc[s];
    }
}

// ---------------------------------------------------------------------------
// Select: exact top-32 (value desc, index asc) + exactness validation:
//   v32_rescored >= thr + EPS proves no below-threshold item can be top-32.
// ---------------------------------------------------------------------------
__global__ __launch_bounds__(64) void select_kernel(
    const float* __restrict__ resc, const u64* __restrict__ emit,
    const int* __restrict__ ccnt, const float* __restrict__ thrv,
    float* __restrict__ tv, int* __restrict__ ti, int* __restrict__ flag,
    int row0)
{
    const int row = row0 + blockIdx.x;
    const int l = threadIdx.x;
    const int cnt = ccnt[row];

    float v[4] = {0.f, 0.f, 0.f, 0.f};
    int   s[4] = {-1, -1, -1, -1};
    u64   p[4] = {0, 0, 0, 0};
#pragma unroll
    for (int j = 0; j < 4; ++j) {
        int c = l + j * 64;
        if (c < cnt) {
            s[j] = (int)(emit[(size_t)row * CAP + c] & 0xFFFFFFFFu);
            v[j] = resc[(size_t)row * CAP + c];
            p[j] = ((u64)key_map(v[j]) << 32) | (unsigned)(~s[j]);
        }
    }

    float* tvr = tv + (size_t)row * TOPK;
    int*   tir = ti + (size_t)row * TOPK;
    float v32f = -3e38f;
#pragma unroll 1
    for (int r = 0; r < TOPK; ++r) {
        u64 m = p[0];
        if (p[1] > m) m = p[1];
        if (p[2] > m) m = p[2];
        if (p[3] > m) m = p[3];
#pragma unroll
        for (int d = 1; d < 64; d <<= 1) {
            u64 o = __shfl_xor(m, d);
            if (o > m) m = o;
        }
        if (r == TOPK - 1) v32f = key_unmap((unsigned)(m >> 32));
        if (p[0] == m)      { tvr[r] = v[0]; tir[r] = s[0] < 0 ? 0 : s[0]; p[0] = 0; }
        else if (p[1] == m) { tvr[r] = v[1]; tir[r] = s[1] < 0 ? 0 : s[1]; p[1] = 0; }
        else if (p[2] == m) { tvr[r] = v[2]; tir[r] = s[2] < 0 ? 0 : s[2]; p[2] = 0; }
        else if (p[3] == m) { tvr[r] = v[3]; tir[r] = s[3] < 0 ? 0 : s[3]; p[3] = 0; }
    }
    if (l == 0) {
        if (v32f < thrv[row] + EPS) flag[row] = 1;
    }
}

// ---------------------------------------------------------------------------
// Fallback (flag-guarded, normally 0 active rows): exact fine-histogram
// screen over the bf16 pre row, then rescore + select.
// ---------------------------------------------------------------------------
__global__ __launch_bounds__(256) void fb_screen_kernel(
    const u16* __restrict__ pre, u64* __restrict__ emit,
    int* __restrict__ ccnt, const int* __restrict__ flag, int row0)
{
    const int grow = row0 + blockIdx.x;
    if (!flag[grow]) return;

    __shared__ unsigned hist[2048];
    __shared__ unsigned partial[256];
    __shared__ unsigned sh_tk;
    __shared__ int cnt;

    const int t = threadIdx.x;
    const u16* prow = pre + (size_t)blockIdx.x * S_DIM;

    for (int i = t; i < 2048; i += 256) hist[i] = 0;
    if (t == 0) cnt = 0;
    __syncthreads();

    for (int i = t * 8; i < S_DIM; i += 2048) {
        short8 v8 = *(const short8*)&prow[i];
#pragma unroll
        for (int j = 0; j < 8; ++j) {
            unsigned k = key_map(bf2f((u16)v8[j]));
            if (k >= 0xC0000000u) atomicAdd(&hist[(k >> 19) - 6144], 1u);
        }
    }
    __syncthreads();

    unsigned ps = 0;
#pragma unroll
    for (int j = 0; j < 8; ++j) ps += hist[t * 8 + j];
    partial[t] = ps;
    __syncthreads();

    if (t == 0) {
        unsigned acc = 0;
        int seg = -1;
        for (int s = 255; s >= 0; --s) {
            if (acc + partial[s] >= (unsigned)TOPK) { seg = s; break; }
            acc += partial[s];
        }
        int bucket = 6144;
        if (seg >= 0) {
            for (int b = seg * 8 + 7; b >= seg * 8; --b) {
                acc += hist[b];
                if (acc >= (unsigned)TOPK) { bucket = 6144 + b; break; }
            }
        }
        float lo = key_unmap(((unsigned)bucket) << 19) - 2.0f * EPS;
        sh_tk = key_map(lo);
    }
    __syncthreads();

    const unsigned TK = sh_tk;
    u64* erow = emit + (size_t)grow * CAP;
    for (int i = t * 8; i < S_DIM; i += 2048) {
        short8 v8 = *(const short8*)&prow[i];
#pragma unroll
        for (int j = 0; j < 8; ++j) {
            unsigned k = key_map(bf2f((u16)v8[j]));
            if (k >= TK) {
                int p = atomicAdd(&cnt, 1);
                if (p < CAP) erow[p] = ((u64)k << 32) | (unsigned)(i + j);
            }
        }
    }
    __syncthreads();
    if (t == 0) ccnt[grow] = (cnt < CAP) ? cnt : CAP;
}

__global__ __launch_bounds__(256) void fb_rescore_kernel(
    const float* __restrict__ x, const float* __restrict__ WT,
    const float* __restrict__ benc, const u64* __restrict__ emit,
    const int* __restrict__ ccnt, float* __restrict__ resc,
    const int* __restrict__ flag, int row0)
{
    const int row = row0 + blockIdx.x;
    if (!flag[row]) return;
    const int t = threadIdx.x;
    const int w = t >> 6, l = t & 63;
    const int cnt = ccnt[row];

    __shared__ float xs[K_DIM];
    const float* xr = x + (size_t)row * K_DIM;
    for (int i = t * 4; i < K_DIM; i += 1024)
        *(float4*)&xs[i] = *(const float4*)&xr[i];
    __syncthreads();

    for (int c = w; c < cnt; c += 4) {
        const int s = (int)(emit[(size_t)row * CAP + c] & 0xFFFFFFFFu);
        const float* wc = WT + (size_t)s * K_DIM;
        float acc = 0.f;
#pragma unroll
        for (int j = 0; j < 32; ++j)
            acc = fmaf(xs[l + 64 * j], wc[l + 64 * j], acc);
#pragma unroll
        for (int d = 1; d < 64; d <<= 1) acc += __shfl_xor(acc, d);
        if (l == 0) resc[(size_t)row * CAP + c] = acc + benc[s];
    }
}

__global__ __launch_bounds__(64) void fb_select_kernel(
    const float* __restrict__ resc, const u64* __restrict__ emit,
    const int* __restrict__ ccnt, float* __restrict__ tv,
    int* __restrict__ ti, const int* __restrict__ flag, int row0)
{
    const int row = row0 + blockIdx.x;
    if (!flag[row]) return;
    const int l = threadIdx.x;
    const int cnt = ccnt[row];

    float v[4] = {0.f, 0.f, 0.f, 0.f};
    int   s[4] = {-1, -1, -1, -1};
    u64   p[4] = {0, 0, 0, 0};
#pragma unroll
    for (int j = 0; j < 4; ++j) {
        int c = l + j * 64;
        if (c < cnt) {
            s[j] = (int)(emit[(size_t)row * CAP + c] & 0xFFFFFFFFu);
            v[j] = resc[(size_t)row * CAP + c];
            p[j] = ((u64)key_map(v[j]) << 32) | (unsigned)(~s[j]);
        }
    }

    float* tvr = tv + (size_t)row * TOPK;
    int*   tir = ti + (size_t)row * TOPK;
#pragma unroll 1
    for (int r = 0; r < TOPK; ++r) {
        u64 m = p[0];
        if (p[1] > m) m = p[1];
        if (p[2] > m) m = p[2];
        if (p[3] > m) m = p[3];
#pragma unroll
        for (int d = 1; d < 64; d <<= 1) {
            u64 o = __shfl_xor(m, d);
            if (o > m) m = o;
        }
        if (p[0] == m)      { tvr[r] = v[0]; tir[r] = s[0] < 0 ? 0 : s[0]; p[0] = 0; }
        else if (p[1] == m) { tvr[r] = v[1]; tir[r] = s[1] < 0 ? 0 : s[1]; p[1] = 0; }
        else if (p[2] == m) { tvr[r] = v[2]; tir[r] = s[2] < 0 ? 0 : s[2]; p[2] = 0; }
        else if (p[3] == m) { tvr[r] = v[3]; tir[r] = s[3] < 0 ? 0 : s[3]; p[3] = 0; }
    }
}

// ---------------------------------------------------------------------------
// Decode (verified): out[row] = b_dec + sum relu(tv)*W_dec[ti]
// ---------------------------------------------------------------------------
__global__ __launch_bounds__(256) void decode_kernel(
    const float* __restrict__ tval, const int* __restrict__ tidx,
    const float* __restrict__ Wd, const float* __restrict__ bdec,
    float* __restrict__ out, int row0)
{
    const int row = row0 + blockIdx.x;
    const int t = threadIdx.x;
    __shared__ float sv[TOPK];
    __shared__ int   si[TOPK];
    if (t < TOPK) {
        sv[t] = fmaxf(tval[(size_t)row * TOPK + t], 0.f);
        si[t] = tidx[(size_t)row * TOPK + t];
    }
    __syncthreads();

    const int c0 = t * 4;
    float4 acc0 = *(const float4*)(bdec + c0);
    float4 acc1 = *(const float4*)(bdec + 1024 + c0);
#pragma unroll 4
    for (int i = 0; i < TOPK; ++i) {
        const float z = sv[i];
        if (z > 0.f) {
            const float* wr = Wd + (size_t)si[i] * K_DIM;
            float4 w0 = *(const float4*)(wr + c0);
            float4 w1 = *(const float4*)(wr + 1024 + c0);
            acc0.x = fmaf(z, w0.x, acc0.x); acc0.y = fmaf(z, w0.y, acc0.y);
            acc0.z = fmaf(z, w0.z, acc0.z); acc0.w = fmaf(z, w0.w, acc0.w);
            acc1.x = fmaf(z, w1.x, acc1.x); acc1.y = fmaf(z, w1.y, acc1.y);
            acc1.z = fmaf(z, w1.z, acc1.z); acc1.w = fmaf(z, w1.w, acc1.w);
        }
    }
    float* op = out + (size_t)row * K_DIM;
    *(float4*)(op + c0) = acc0;
    *(float4*)(op + 1024 + c0) = acc1;
}

// ---------------------------------------------------------------------------
extern "C" void kernel_launch(void* const* d_in, const int* in_sizes, int n_in,
                              void* d_out, int out_size, void* d_ws, size_t ws_size,
                              hipStream_t stream)
{
    const float* x     = (const float*)d_in[0];
    const float* W_enc = (const float*)d_in[1];
    const float* W_dec = (const float*)d_in[2];
    const float* b_enc = (const float*)d_in[3];
    const float* b_dec = (const float*)d_in[4];
    float* out = (float*)d_out;

    const int M = in_sizes[0] / K_DIM;   // 4096 batch rows

    // ws layout: tv | ti | emit | ccnt | thrv | flag | resc | Xh | Wh | WT | pre(bf16)
    char* wsb = (char*)d_ws;
    size_t o = 0;
    float*    tv   = (float*)(wsb + o);    o += (size_t)M * TOPK * 4;
    int*      ti   = (int*)(wsb + o);      o += (size_t)M * TOPK * 4;
    u64*      emit = (u64*)(wsb + o);      o += (size_t)M * CAP * 8;
    int*      ccnt = (int*)(wsb + o);      o += (size_t)M * 4;
    float*    thrv = (float*)(wsb + o);    o += (size_t)M * 4;
    int*      flag = (int*)(wsb + o);      o += (size_t)M * 4;
    float*    resc = (float*)(wsb + o);    o += (size_t)M * CAP * 4;
    u16*      Xh   = (u16*)(wsb + o);      o += (size_t)M * K_DIM * 2;
    u16*      Wh   = (u16*)(wsb + o);      o += (size_t)S_DIM * K_DIM * 2;
    float*    WT   = (float*)(wsb + o);    o += (size_t)S_DIM * K_DIM * 4;
    u16*      pre  = (u16*)(wsb + o);

    size_t cap = (ws_size > o) ? (ws_size - o) : 0;
    long cap_rows = (long)(cap / ((size_t)S_DIM * 2));
    int chunk = (int)((cap_rows / 256) * 256);
    if (chunk <= 0) chunk = 256;
    if (chunk > M) chunk = M;

    init_kernel<<<(M + 255) / 256, 256, 0, stream>>>(flag, M);
    const int n4 = M * K_DIM / 4;
    conv_x_kernel<<<(n4 + 255) / 256, 256, 0, stream>>>(x, Xh, n4);
    conv_wt_kernel<<<dim3(S_DIM / 64, K_DIM / 64), 256, 0, stream>>>(W_enc, WT, Wh);

    for (int r0 = 0; r0 < M; r0 += chunk) {
        const int rows = (M - r0 < chunk) ? (M - r0) : chunk;
        const int nbm = rows / 256;
        gemm_mfma_kernel<<<nbm * 128, 512, 0, stream>>>(
            Xh + (size_t)r0 * K_DIM, Wh, b_enc, pre);
        screen_kernel<<<rows, 256, 0, stream>>>(pre, emit, ccnt, thrv, flag, r0);
        rescore_kernel<<<rows, 256, 0, stream>>>(x, WT, b_enc, emit, ccnt, thrv, resc, r0);
        select_kernel<<<rows, 64, 0, stream>>>(resc, emit, ccnt, thrv, tv, ti, flag, r0);
        fb_screen_kernel<<<rows, 256, 0, stream>>>(pre, emit, ccnt, flag, r0);
        fb_rescore_kernel<<<rows, 256, 0, stream>>>(x, WT, b_enc, emit, ccnt, resc, flag, r0);
        fb_select_kernel<<<rows, 64, 0, stream>>>(resc, emit, ccnt, tv, ti, flag, r0);
        decode_kernel<<<rows, 256, 0, stream>>>(tv, ti, W_dec, b_dec, out, r0);
    }
}

// Round 11
// 1070.302 us; speedup vs baseline: 1.4200x; 1.0128x over previous
//
#include <hip/hip_runtime.h>
#include <cstdint>
#include <cstddef>

typedef unsigned short u16;
typedef unsigned long long u64;
typedef __attribute__((ext_vector_type(8))) short short8;   // 8 x bf16 fragment
typedef __attribute__((ext_vector_type(4))) float f32x4;    // MFMA accumulator

constexpr int K_DIM = 2048;    // N_POS * D_MODEL (contraction dim for encode)
constexpr int S_DIM = 32768;   // D_SAE
constexpr int TOPK  = 32;
constexpr int CAP   = 256;     // max candidates per row (4 x 64 lanes in select)
#define EPS      0.07f         // bf16-GEMM error (0.06, r3-r8 proven) + bf16-pre rounding
#define THR_EMIT 3.7f          // collect floor (needs v32a >= 3.84; 7-sigma safe)
#define HIST_LO  3.5f          // histogram floor, 64 buckets of width 0.04

// ---------------------------------------------------------------------------
__device__ __forceinline__ u16 f2bf(float f) {
    unsigned u = __float_as_uint(f);
    return (u16)((u + 0x7FFFu + ((u >> 16) & 1u)) >> 16);
}
__device__ __forceinline__ float bf2f(u16 h) {
    return __uint_as_float(((unsigned)h) << 16);
}
__device__ __forceinline__ unsigned key_map(float f) {
    unsigned u = __float_as_uint(f);
    return (u & 0x80000000u) ? ~u : (u | 0x80000000u);
}
__device__ __forceinline__ float key_unmap(unsigned k) {
    unsigned u = (k & 0x80000000u) ? (k ^ 0x80000000u) : ~k;
    return __uint_as_float(u);
}

// x fp32 -> bf16 (for MFMA screening)
__global__ __launch_bounds__(256) void conv_x_kernel(
    const float* __restrict__ x, u16* __restrict__ hi, int n4)
{
    int i = blockIdx.x * 256 + threadIdx.x;
    if (i >= n4) return;
    float4 v = ((const float4*)x)[i];
    ushort4 h;
    h.x = f2bf(v.x); h.y = f2bf(v.y); h.z = f2bf(v.z); h.w = f2bf(v.w);
    ((ushort4*)hi)[i] = h;
}

// W_enc [K][S] f32 -> WT [S][K] f32 (exact, for rescoring) + Wh [S][K] bf16.
__global__ __launch_bounds__(256) void conv_wt_kernel(
    const float* __restrict__ W, float* __restrict__ WT, u16* __restrict__ Wh)
{
    __shared__ float tile[64][65];
    const int t  = threadIdx.x;
    const int s0 = blockIdx.x * 64;
    const int k0 = blockIdx.y * 64;
#pragma unroll
    for (int i = 0; i < 4; ++i) {
        int kl = (t >> 4) + i * 16;
        int sc = (t & 15) * 4;
        float4 v = *(const float4*)&W[(size_t)(k0 + kl) * S_DIM + s0 + sc];
        tile[kl][sc] = v.x; tile[kl][sc + 1] = v.y;
        tile[kl][sc + 2] = v.z; tile[kl][sc + 3] = v.w;
    }
    __syncthreads();
    const int klc = (t & 7) * 8;
#pragma unroll
    for (int i = 0; i < 2; ++i) {
        int sl = (t >> 3) + i * 32;
        float f[8];
        short8 h8;
#pragma unroll
        for (int j = 0; j < 8; ++j) {
            f[j] = tile[klc + j][sl];
            h8[j] = (short)f2bf(f[j]);
        }
        size_t o = (size_t)(s0 + sl) * K_DIM + k0 + klc;
        *(float4*)&WT[o]     = make_float4(f[0], f[1], f[2], f[3]);
        *(float4*)&WT[o + 4] = make_float4(f[4], f[5], f[6], f[7]);
        *(short8*)&Wh[o] = h8;
    }
}

// ---------------------------------------------------------------------------
// Screening GEMM, 256x256, r10 K-loop (byte-identical). Epilogue LDS
// transpose now chunk-swizzled: chunk ^= ((row>>2)&3)<<1 on write AND read —
// spreads the 4 kq row-groups (512B row stride aliases banks mod 32) onto
// disjoint chunk pairs -> 2 lanes/bank-word (free). Read side: per-row full
// chunk permutation, still conflict-free.
// ---------------------------------------------------------------------------
__device__ __forceinline__ void gl16(const u16* g, u16* s) {
    __builtin_amdgcn_global_load_lds(
        (const __attribute__((address_space(1))) unsigned int*)g,
        (__attribute__((address_space(3))) unsigned int*)s,
        16, 0, 0);
}

#define LGKM0  do { asm volatile("s_waitcnt lgkmcnt(0)" ::: "memory"); \
                    __builtin_amdgcn_sched_barrier(0); } while (0)
#define VMW(n) asm volatile("s_waitcnt vmcnt(" #n ")" ::: "memory")
#define BAR    do { __builtin_amdgcn_s_barrier(); \
                    __builtin_amdgcn_sched_barrier(0); } while (0)

__global__ __launch_bounds__(512, 2) void gemm_mfma_kernel(
    const u16* __restrict__ A, const u16* __restrict__ B,
    const float* __restrict__ bias, u16* __restrict__ Cb)
{
    __shared__ alignas(16) u16 sMem[65536];   // sA[2][16384] | sB[2][16384]
    u16* sA0 = sMem;
    u16* sB0 = sMem + 32768;

    const int t = threadIdx.x;
    const int lane = t & 63;
    const int w = t >> 6;
    const int wm = w >> 2, wn = w & 3;

    const int nwg = gridDim.x;
    const int q = nwg >> 3;
    const int bid = blockIdx.x;
    const int wg = (bid & 7) * q + (bid >> 3);
    const int bm = wg >> 7;
    const int bn = wg & 127;

    const u16* Ab = A + (size_t)bm * 256 * K_DIM;
    const u16* Bb = B + (size_t)bn * 256 * K_DIM;

    const int w2  = w * 2;
    const int lr3 = lane >> 3;
    const int csw = ((lane & 7) ^ lr3) * 8;

    const int rl = lane & 15, kq = lane >> 4;
    const int swz = rl & 7;
    const int ac0 = (kq ^ swz) * 8;
    const int ac1 = ((4 + kq) ^ swz) * 8;
    const int arow = (wm * 16 + rl) * 64;
    const int brow = (wn * 16 + rl) * 64;

    f32x4 acc[8][4];
#pragma unroll
    for (int m = 0; m < 8; ++m)
#pragma unroll
        for (int n = 0; n < 4; ++n) acc[m][n] = (f32x4){0.f, 0.f, 0.f, 0.f};

    auto stA = [&](int half, int j, int kt, int buf) {
        const u16* src = Ab + (size_t)(half * 128 + (w2 + j) * 8 + lr3) * K_DIM
                            + kt * 64 + csw;
        gl16(src, sA0 + buf * 16384 + half * 8192 + (w2 + j) * 512);
    };
    auto stB = [&](int half, int j, int kt, int buf) {
        const u16* src = Bb + (size_t)(half * 128 + (w2 + j) * 8 + lr3) * K_DIM
                            + kt * 64 + csw;
        gl16(src, sB0 + buf * 16384 + half * 8192 + (w2 + j) * 512);
    };

    // Prologue: 7 halves in steady-state FIFO order; drain tile 0 (leave 6).
    stB(0, 0, 0, 0); stB(0, 1, 0, 0);   // Bh0(0)
    stA(0, 0, 0, 0); stA(0, 1, 0, 0);   // Ah0(0)
    stB(1, 0, 0, 0); stB(1, 1, 0, 0);   // Bh1(0)
    stA(1, 0, 0, 0); stA(1, 1, 0, 0);   // Ah1(0)
    stB(0, 0, 1, 1); stB(0, 1, 1, 1);   // Bh0(1)
    stA(0, 0, 1, 1); stA(0, 1, 1, 1);   // Ah0(1)
    stB(1, 0, 1, 1); stB(1, 1, 1, 1);   // Bh1(1)
    VMW(6);
    BAR;

    short8 af[4][2], bf[4][2];

    // preload tile-0 B n0-1 fragments (buf 0)
#pragma unroll
    for (int n = 0; n < 2; ++n) {
        bf[n][0] = *(const short8*)&sB0[brow + n * 4096 + ac0];
        bf[n][1] = *(const short8*)&sB0[brow + n * 4096 + ac1];
    }

#pragma unroll 1
    for (int it = 0; it < 16; ++it) {
        const bool lastIt = (it == 15);
#pragma unroll
        for (int h = 0; h < 2; ++h) {
            const int b  = h;                  // buffer read this half-iter
            const int tA = 2 * it + 1 + h;     // Ah1 stage tile -> buf b^1
            const int tB = 2 * it + 2 + h;     // Bh0/Ah0/Bh1 stage tile -> buf b

            // ---- ph1: read A m0-3 (8 reads); stage Ah1(tA)
#pragma unroll
            for (int m = 0; m < 4; ++m) {
                af[m][0] = *(const short8*)&sA0[b * 16384 + arow + m * 2048 + ac0];
                af[m][1] = *(const short8*)&sA0[b * 16384 + arow + m * 2048 + ac1];
            }
            if (tA < 32) { stA(1, 0, tA, b ^ 1); stA(1, 1, tA, b ^ 1); }
            __builtin_amdgcn_s_barrier();
            LGKM0;
            __builtin_amdgcn_s_setprio(1);
#pragma unroll
            for (int m = 0; m < 4; ++m)
#pragma unroll
                for (int n = 0; n < 2; ++n)
#pragma unroll
                    for (int kk = 0; kk < 2; ++kk)
                        acc[m][n] = __builtin_amdgcn_mfma_f32_16x16x32_bf16(
                            af[m][kk], bf[n][kk], acc[m][n], 0, 0, 0);
            __builtin_amdgcn_s_setprio(0);
            BAR;

            // ---- ph2: read B n2-3 (4 reads); stage Bh0(tB)
#pragma unroll
            for (int n = 2; n < 4; ++n) {
                bf[n][0] = *(const short8*)&sB0[b * 16384 + brow + n * 4096 + ac0];
                bf[n][1] = *(const short8*)&sB0[b * 16384 + brow + n * 4096 + ac1];
            }
            if (tB < 32) { stB(0, 0, tB, b); stB(0, 1, tB, b); }
            __builtin_amdgcn_s_barrier();
            LGKM0;
            __builtin_amdgcn_s_setprio(1);
#pragma unroll
            for (int m = 0; m < 4; ++m)
#pragma unroll
                for (int n = 2; n < 4; ++n)
#pragma unroll
                    for (int kk = 0; kk < 2; ++kk)
                        acc[m][n] = __builtin_amdgcn_mfma_f32_16x16x32_bf16(
                            af[m][kk], bf[n][kk], acc[m][n], 0, 0, 0);
            __builtin_amdgcn_s_setprio(0);
            BAR;

            // ---- ph3: read A m4-7 (8 reads); stage Ah0(tB)
#pragma unroll
            for (int m = 0; m < 4; ++m) {
                af[m][0] = *(const short8*)&sA0[b * 16384 + arow + (m + 4) * 2048 + ac0];
                af[m][1] = *(const short8*)&sA0[b * 16384 + arow + (m + 4) * 2048 + ac1];
            }
            if (tB < 32) { stA(0, 0, tB, b); stA(0, 1, tB, b); }
            __builtin_amdgcn_s_barrier();
            LGKM0;
            __builtin_amdgcn_s_setprio(1);
#pragma unroll
            for (int m = 0; m < 4; ++m)
#pragma unroll
                for (int n = 2; n < 4; ++n)
#pragma unroll
                    for (int kk = 0; kk < 2; ++kk)
                        acc[m + 4][n] = __builtin_amdgcn_mfma_f32_16x16x32_bf16(
                            af[m][kk], bf[n][kk], acc[m + 4][n], 0, 0, 0);
            __builtin_amdgcn_s_setprio(0);
            BAR;

            // ---- ph4: stage Bh1(tB); MFMA m4-7 x n0-1; counted wait;
            //           then read NEXT tile's B n0-1 (4 reads, post-VMW)
            if (tB < 32) { stB(1, 0, tB, b); stB(1, 1, tB, b); }
            __builtin_amdgcn_s_barrier();
            __builtin_amdgcn_s_setprio(1);
#pragma unroll
            for (int m = 0; m < 4; ++m)
#pragma unroll
                for (int n = 0; n < 2; ++n)
#pragma unroll
                    for (int kk = 0; kk < 2; ++kk)
                        acc[m + 4][n] = __builtin_amdgcn_mfma_f32_16x16x32_bf16(
                            af[m][kk], bf[n][kk], acc[m + 4][n], 0, 0, 0);
            __builtin_amdgcn_s_setprio(0);
            if (lastIt && h == 0) { VMW(0); } else { VMW(6); }
            if (!(lastIt && h == 1)) {
#pragma unroll
                for (int n = 0; n < 2; ++n) {
                    bf[n][0] = *(const short8*)&sB0[(b ^ 1) * 16384 + brow + n * 4096 + ac0];
                    bf[n][1] = *(const short8*)&sB0[(b ^ 1) * 16384 + brow + n * 4096 + ac1];
                }
            }
            BAR;
        }
    }

    // ---- epilogue: acc -> bf16 LDS tile [256][256] (chunk-swizzled) ->
    // coalesced short8 stores. C/D layout: col = lane&15, row = (lane>>4)*4+reg.
    {
        const int colL = wn * 16 + rl;        // + n*64
        const int rowL = wm * 16 + kq * 4;    // + m*32 + rr
        float bv[4];
#pragma unroll
        for (int n = 0; n < 4; ++n) bv[n] = bias[bn * 256 + colL + n * 64];
#pragma unroll
        for (int m = 0; m < 8; ++m)
#pragma unroll
            for (int n = 0; n < 4; ++n)
#pragma unroll
                for (int rr = 0; rr < 4; ++rr) {
                    const int row = rowL + m * 32 + rr;
                    const int col = colL + n * 64;
                    const int chs = (col >> 3) ^ (((row >> 2) & 3) << 1);
                    sMem[row * 256 + (chs << 3) + (col & 7)] =
                        f2bf(acc[m][n][rr] + bv[n]);
                }
        __syncthreads();

        const int rr2 = t >> 5;               // 0..15
        const int c16 = t & 31;               // 16B chunk in row
        const size_t growB = (size_t)bm * 256;
#pragma unroll
        for (int r = 0; r < 16; ++r) {
            const int lrow = r * 16 + rr2;
            const int chr = c16 ^ (((lrow >> 2) & 3) << 1);
            short8 v = *(const short8*)&sMem[lrow * 256 + (chr << 3)];
            *(short8*)&Cb[(growB + lrow) * S_DIM + bn * 256 + c16 * 8] = v;
        }
    }
}

// ---------------------------------------------------------------------------
// Fused per-row tail: screen (64-bucket hist + collect + suffix scan) ->
// rescore (exact fp32, order identical to r3-r10) -> select (wave 0) ->
// decode. All intermediates in LDS; single unconditional flag write.
// ---------------------------------------------------------------------------
__global__ __launch_bounds__(256) void fused_kernel(
    const u16* __restrict__ pre, const float* __restrict__ x,
    const float* __restrict__ WT, const float* __restrict__ benc,
    const float* __restrict__ Wd, const float* __restrict__ bdec,
    float* __restrict__ out, int* __restrict__ flag, int row0)
{
    __shared__ unsigned hist[64];
    __shared__ int cnt;
    __shared__ float sh_thr;
    __shared__ int sh_bad;
    __shared__ u64 emitL[CAP];
    __shared__ float rescL[CAP];
    __shared__ float xs[K_DIM];
    __shared__ float tvL[TOPK];
    __shared__ int   tiL[TOPK];

    const int t = threadIdx.x;
    const int row = blockIdx.x;           // chunk-local
    const int grow = row0 + row;
    const u16* prow = pre + (size_t)row * S_DIM;

    if (t < 64) hist[t] = 0;
    if (t == 0) { cnt = 0; sh_bad = 0; }
    __syncthreads();

    // stage x row + screen pass
    const float* xr = x + (size_t)grow * K_DIM;
    for (int i = t * 4; i < K_DIM; i += 1024)
        *(float4*)&xs[i] = *(const float4*)&xr[i];

    for (int i = t * 8; i < S_DIM; i += 2048) {
        short8 v8 = *(const short8*)&prow[i];
#pragma unroll
        for (int j = 0; j < 8; ++j) {
            float v = bf2f((u16)v8[j]);
            if (v >= HIST_LO) {
                int b = (int)((v - HIST_LO) * 25.0f);
                if (b > 63) b = 63;
                atomicAdd(&hist[b], 1u);
                if (v >= THR_EMIT) {
                    int p = atomicAdd(&cnt, 1);
                    if (p < CAP)
                        emitL[p] = ((u64)key_map(v) << 32) | (unsigned)(i + j);
                }
            }
        }
    }
    __syncthreads();

    if (t == 0) {
        unsigned acc = 0;
        int b = -1;
        for (int j = 63; j >= 0; --j) {
            acc += hist[j];
            if (acc >= (unsigned)TOPK) { b = j; break; }
        }
        float thr = HIST_LO + 0.04f * b - 2.0f * EPS - 1e-4f;
        if (b < 0 || cnt > CAP || thr < THR_EMIT) {
            sh_bad = 1;
            thr = THR_EMIT;
        }
        sh_thr = thr;
    }
    __syncthreads();

    const int cntc = (cnt < CAP) ? cnt : CAP;
    const float thr = sh_thr;
    const int wv = t >> 6, l = t & 63;

    // rescore (summation order identical to r3-r10)
    for (int c = wv; c < cntc; c += 4) {
        const u64 pk = emitL[c];
        const float approx = key_unmap((unsigned)(pk >> 32));
        if (approx < thr) {
            if (l == 0) rescL[c] = -3e38f;
            continue;
        }
        const int s = (int)(pk & 0xFFFFFFFFu);
        const float* wc = WT + (size_t)s * K_DIM;
        float acc = 0.f;
#pragma unroll
        for (int j = 0; j < 32; ++j)
            acc = fmaf(xs[l + 64 * j], wc[l + 64 * j], acc);
#pragma unroll
        for (int d = 1; d < 64; d <<= 1) acc += __shfl_xor(acc, d);
        if (l == 0) rescL[c] = acc + benc[s];
    }
    __syncthreads();

    // select: wave 0 only (exact top-32, value desc / index asc) + validation
    if (t < 64) {
        float v[4] = {0.f, 0.f, 0.f, 0.f};
        int   s[4] = {-1, -1, -1, -1};
        u64   p[4] = {0, 0, 0, 0};
#pragma unroll
        for (int j = 0; j < 4; ++j) {
            int c = l + j * 64;
            if (c < cntc) {
                s[j] = (int)(emitL[c] & 0xFFFFFFFFu);
                v[j] = rescL[c];
                p[j] = ((u64)key_map(v[j]) << 32) | (unsigned)(~s[j]);
            }
        }
        float v32f = -3e38f;
#pragma unroll 1
        for (int r = 0; r < TOPK; ++r) {
            u64 m = p[0];
            if (p[1] > m) m = p[1];
            if (p[2] > m) m = p[2];
            if (p[3] > m) m = p[3];
#pragma unroll
            for (int d = 1; d < 64; d <<= 1) {
                u64 o = __shfl_xor(m, d);
                if (o > m) m = o;
            }
            if (r == TOPK - 1) v32f = key_unmap((unsigned)(m >> 32));
            if (p[0] == m)      { tvL[r] = v[0]; tiL[r] = s[0] < 0 ? 0 : s[0]; p[0] = 0; }
            else if (p[1] == m) { tvL[r] = v[1]; tiL[r] = s[1] < 0 ? 0 : s[1]; p[1] = 0; }
            else if (p[2] == m) { tvL[r] = v[2]; tiL[r] = s[2] < 0 ? 0 : s[2]; p[2] = 0; }
            else if (p[3] == m) { tvL[r] = v[3]; tiL[r] = s[3] < 0 ? 0 : s[3]; p[3] = 0; }
        }
        if (l == 0)
            flag[grow] = (sh_bad || v32f < thr + EPS) ? 1 : 0;
    }
    __syncthreads();

    // decode (flagged rows get overwritten by fb_kernel afterwards)
    const int c0 = t * 4;
    float4 acc0 = *(const float4*)(bdec + c0);
    float4 acc1 = *(const float4*)(bdec + 1024 + c0);
#pragma unroll 4
    for (int i = 0; i < TOPK; ++i) {
        const float z = fmaxf(tvL[i], 0.f);
        if (z > 0.f) {
            const float* wr = Wd + (size_t)tiL[i] * K_DIM;
            float4 w0 = *(const float4*)(wr + c0);
            float4 w1 = *(const float4*)(wr + 1024 + c0);
            acc0.x = fmaf(z, w0.x, acc0.x); acc0.y = fmaf(z, w0.y, acc0.y);
            acc0.z = fmaf(z, w0.z, acc0.z); acc0.w = fmaf(z, w0.w, acc0.w);
            acc1.x = fmaf(z, w1.x, acc1.x); acc1.y = fmaf(z, w1.y, acc1.y);
            acc1.z = fmaf(z, w1.z, acc1.z); acc1.w = fmaf(z, w1.w, acc1.w);
        }
    }
    float* op = out + (size_t)grow * K_DIM;
    *(float4*)(op + c0) = acc0;
    *(float4*)(op + 1024 + c0) = acc1;
}

// ---------------------------------------------------------------------------
// Fused fallback (flag-guarded, normally 0 active rows): exact fine-histogram
// screen -> rescore all -> select -> decode, all in one kernel.
// ---------------------------------------------------------------------------
__global__ __launch_bounds__(256) void fb_kernel(
    const u16* __restrict__ pre, const float* __restrict__ x,
    const float* __restrict__ WT, const float* __restrict__ benc,
    const float* __restrict__ Wd, const float* __restrict__ bdec,
    float* __restrict__ out, const int* __restrict__ flag, int row0)
{
    const int row = blockIdx.x;
    const int grow = row0 + row;
    if (!flag[grow]) return;

    __shared__ unsigned hist[2048];
    __shared__ unsigned partial[256];
    __shared__ unsigned sh_tk;
    __shared__ int cnt;
    __shared__ u64 emitL[CAP];
    __shared__ float rescL[CAP];
    __shared__ float xs[K_DIM];
    __shared__ float tvL[TOPK];
    __shared__ int   tiL[TOPK];

    const int t = threadIdx.x;
    const u16* prow = pre + (size_t)row * S_DIM;

    for (int i = t; i < 2048; i += 256) hist[i] = 0;
    if (t == 0) cnt = 0;
    __syncthreads();

    const float* xr = x + (size_t)grow * K_DIM;
    for (int i = t * 4; i < K_DIM; i += 1024)
        *(float4*)&xs[i] = *(const float4*)&xr[i];

    for (int i = t * 8; i < S_DIM; i += 2048) {
        short8 v8 = *(const short8*)&prow[i];
#pragma unroll
        for (int j = 0; j < 8; ++j) {
            unsigned k = key_map(bf2f((u16)v8[j]));
            if (k >= 0xC0000000u) atomicAdd(&hist[(k >> 19) - 6144], 1u);
        }
    }
    __syncthreads();

    unsigned ps = 0;
#pragma unroll
    for (int j = 0; j < 8; ++j) ps += hist[t * 8 + j];
    partial[t] = ps;
    __syncthreads();

    if (t == 0) {
        unsigned acc = 0;
        int seg = -1;
        for (int s = 255; s >= 0; --s) {
            if (acc + partial[s] >= (unsigned)TOPK) { seg = s; break; }
            acc += partial[s];
        }
        int bucket = 6144;
        if (seg >= 0) {
            for (int b = seg * 8 + 7; b >= seg * 8; --b) {
                acc += hist[b];
                if (acc >= (unsigned)TOPK) { bucket = 6144 + b; break; }
            }
        }
        float lo = key_unmap(((unsigned)bucket) << 19) - 2.0f * EPS;
        sh_tk = key_map(lo);
    }
    __syncthreads();

    const unsigned TK = sh_tk;
    for (int i = t * 8; i < S_DIM; i += 2048) {
        short8 v8 = *(const short8*)&prow[i];
#pragma unroll
        for (int j = 0; j < 8; ++j) {
            unsigned k = key_map(bf2f((u16)v8[j]));
            if (k >= TK) {
                int p = atomicAdd(&cnt, 1);
                if (p < CAP) emitL[p] = ((u64)k << 32) | (unsigned)(i + j);
            }
        }
    }
    __syncthreads();

    const int cntc = (cnt < CAP) ? cnt : CAP;
    const int wv = t >> 6, l = t & 63;

    for (int c = wv; c < cntc; c += 4) {
        const int s = (int)(emitL[c] & 0xFFFFFFFFu);
        const float* wc = WT + (size_t)s * K_DIM;
        float acc = 0.f;
#pragma unroll
        for (int j = 0; j < 32; ++j)
            acc = fmaf(xs[l + 64 * j], wc[l + 64 * j], acc);
#pragma unroll
        for (int d = 1; d < 64; d <<= 1) acc += __shfl_xor(acc, d);
        if (l == 0) rescL[c] = acc + benc[s];
    }
    __syncthreads();

    if (t < 64) {
        float v[4] = {0.f, 0.f, 0.f, 0.f};
        int   s[4] = {-1, -1, -1, -1};
        u64   p[4] = {0, 0, 0, 0};
#pragma unroll
        for (int j = 0; j < 4; ++j) {
            int c = l + j * 64;
            if (c < cntc) {
                s[j] = (int)(emitL[c] & 0xFFFFFFFFu);
                v[j] = rescL[c];
                p[j] = ((u64)key_map(v[j]) << 32) | (unsigned)(~s[j]);
            }
        }
#pragma unroll 1
        for (int r = 0; r < TOPK; ++r) {
            u64 m = p[0];
            if (p[1] > m) m = p[1];
            if (p[2] > m) m = p[2];
            if (p[3] > m) m = p[3];
#pragma unroll
            for (int d = 1; d < 64; d <<= 1) {
                u64 o = __shfl_xor(m, d);
                if (o > m) m = o;
            }
            if (p[0] == m)      { tvL[r] = v[0]; tiL[r] = s[0] < 0 ? 0 : s[0]; p[0] = 0; }
            else if (p[1] == m) { tvL[r] = v[1]; tiL[r] = s[1] < 0 ? 0 : s[1]; p[1] = 0; }
            else if (p[2] == m) { tvL[r] = v[2]; tiL[r] = s[2] < 0 ? 0 : s[2]; p[2] = 0; }
            else if (p[3] == m) { tvL[r] = v[3]; tiL[r] = s[3] < 0 ? 0 : s[3]; p[3] = 0; }
        }
    }
    __syncthreads();

    const int c0 = t * 4;
    float4 acc0 = *(const float4*)(bdec + c0);
    float4 acc1 = *(const float4*)(bdec + 1024 + c0);
#pragma unroll 4
    for (int i = 0; i < TOPK; ++i) {
        const float z = fmaxf(tvL[i], 0.f);
        if (z > 0.f) {
            const float* wr = Wd + (size_t)tiL[i] * K_DIM;
            float4 w0 = *(const float4*)(wr + c0);
            float4 w1 = *(const float4*)(wr + 1024 + c0);
            acc0.x = fmaf(z, w0.x, acc0.x); acc0.y = fmaf(z, w0.y, acc0.y);
            acc0.z = fmaf(z, w0.z, acc0.z); acc0.w = fmaf(z, w0.w, acc0.w);
            acc1.x = fmaf(z, w1.x, acc1.x); acc1.y = fmaf(z, w1.y, acc1.y);
            acc1.z = fmaf(z, w1.z, acc1.z); acc1.w = fmaf(z, w1.w, acc1.w);
        }
    }
    float* op = out + (size_t)grow * K_DIM;
    *(float4*)(op + c0) = acc0;
    *(float4*)(op + 1024 + c0) = acc1;
}

// ---------------------------------------------------------------------------
extern "C" void kernel_launch(void* const* d_in, const int* in_sizes, int n_in,
                              void* d_out, int out_size, void* d_ws, size_t ws_size,
                              hipStream_t stream)
{
    const float* x     = (const float*)d_in[0];
    const float* W_enc = (const float*)d_in[1];
    const float* W_dec = (const float*)d_in[2];
    const float* b_enc = (const float*)d_in[3];
    const float* b_dec = (const float*)d_in[4];
    float* out = (float*)d_out;

    const int M = in_sizes[0] / K_DIM;   // 4096 batch rows

    // ws layout: flag | Xh | Wh | WT | pre(bf16)
    char* wsb = (char*)d_ws;
    size_t o = 0;
    int*   flag = (int*)(wsb + o);   o += (size_t)M * 4;
    u16*   Xh   = (u16*)(wsb + o);   o += (size_t)M * K_DIM * 2;
    u16*   Wh   = (u16*)(wsb + o);   o += (size_t)S_DIM * K_DIM * 2;
    float* WT   = (float*)(wsb + o); o += (size_t)S_DIM * K_DIM * 4;
    u16*   pre  = (u16*)(wsb + o);

    size_t cap = (ws_size > o) ? (ws_size - o) : 0;
    long cap_rows = (long)(cap / ((size_t)S_DIM * 2));
    int chunk = (int)((cap_rows / 256) * 256);
    if (chunk <= 0) chunk = 256;
    if (chunk > M) chunk = M;

    const int n4 = M * K_DIM / 4;
    conv_x_kernel<<<(n4 + 255) / 256, 256, 0, stream>>>(x, Xh, n4);
    conv_wt_kernel<<<dim3(S_DIM / 64, K_DIM / 64), 256, 0, stream>>>(W_enc, WT, Wh);

    for (int r0 = 0; r0 < M; r0 += chunk) {
        const int rows = (M - r0 < chunk) ? (M - r0) : chunk;
        const int nbm = rows / 256;
        gemm_mfma_kernel<<<nbm * 128, 512, 0, stream>>>(
            Xh + (size_t)r0 * K_DIM, Wh, b_enc, pre);
        fused_kernel<<<rows, 256, 0, stream>>>(
            pre, x, WT, b_enc, W_dec, b_dec, out, flag, r0);
        fb_kernel<<<rows, 256, 0, stream>>>(
            pre, x, WT, b_enc, W_dec, b_dec, out, flag, r0);
    }
}